// Round 14
// baseline (328.573 us; speedup 1.0000x reference)
//
#include <hip/hip_runtime.h>

#define N 4096
#define D 512
#define BIG 1e30f
#define CMAX 2048
#define CMAX2 1024
#define NW (N / 32)
#define CH 16            // member rows per colmin task
#define TMAX 2304        // max tasks = CMAX + N/CH
#define NT (N / 128)     // 32 tiles per dim
#define NTRI (NT * (NT + 1) / 2)   // 528 upper-tri tile pairs

typedef unsigned long long u64;
typedef unsigned short u16;
typedef _Float16 f16x8 __attribute__((ext_vector_type(8)));
typedef float floatx4 __attribute__((ext_vector_type(4)));

// ---------------- fused prep: f32->f16 convert + row sq-norms + repr partial + ALL init
__global__ __launch_bounds__(256) void prep_kernel(const float* __restrict__ x1,
                                                   const float* __restrict__ x2,
                                                   u16* __restrict__ h1,
                                                   u16* __restrict__ h2,
                                                   float* __restrict__ sq,
                                                   float* __restrict__ accumArr,
                                                   int* __restrict__ comp,
                                                   u64* __restrict__ compBest,
                                                   int* __restrict__ comp_c) {
    const int tid = blockIdx.x * 256 + threadIdx.x;
    if (tid < 2 * N) {
        comp[tid] = tid & (N - 1);
        compBest[tid] = ~0ull;
    }
    if (tid < 2 * CMAX) comp_c[tid] = tid & (CMAX - 1);

    const int wave = threadIdx.x >> 6, lane = threadIdx.x & 63;
    const int row = blockIdx.x * 4 + wave;
    const float4* r1 = (const float4*)(x1 + (size_t)row * D);
    const float4* r2 = (const float4*)(x2 + (size_t)row * D);
    float4 a0 = r1[lane * 2], a1 = r1[lane * 2 + 1];
    float4 b0 = r2[lane * 2], b1 = r2[lane * 2 + 1];
    ushort4* o1 = (ushort4*)(h1 + (size_t)row * D + lane * 8);
    ushort4* o2 = (ushort4*)(h2 + (size_t)row * D + lane * 8);
    o1[0] = make_ushort4(__builtin_bit_cast(u16, (_Float16)a0.x), __builtin_bit_cast(u16, (_Float16)a0.y),
                         __builtin_bit_cast(u16, (_Float16)a0.z), __builtin_bit_cast(u16, (_Float16)a0.w));
    o1[1] = make_ushort4(__builtin_bit_cast(u16, (_Float16)a1.x), __builtin_bit_cast(u16, (_Float16)a1.y),
                         __builtin_bit_cast(u16, (_Float16)a1.z), __builtin_bit_cast(u16, (_Float16)a1.w));
    o2[0] = make_ushort4(__builtin_bit_cast(u16, (_Float16)b0.x), __builtin_bit_cast(u16, (_Float16)b0.y),
                         __builtin_bit_cast(u16, (_Float16)b0.z), __builtin_bit_cast(u16, (_Float16)b0.w));
    o2[1] = make_ushort4(__builtin_bit_cast(u16, (_Float16)b1.x), __builtin_bit_cast(u16, (_Float16)b1.y),
                         __builtin_bit_cast(u16, (_Float16)b1.z), __builtin_bit_cast(u16, (_Float16)b1.w));
    float s1 = 0.f, s2 = 0.f, sr = 0.f;
    float av[8] = {a0.x, a0.y, a0.z, a0.w, a1.x, a1.y, a1.z, a1.w};
    float bv[8] = {b0.x, b0.y, b0.z, b0.w, b1.x, b1.y, b1.z, b1.w};
#pragma unroll
    for (int e = 0; e < 8; ++e) {
        s1 = fmaf(av[e], av[e], s1);
        s2 = fmaf(bv[e], bv[e], s2);
        float d = av[e] - bv[e];
        sr = fmaf(d, d, sr);
    }
#pragma unroll
    for (int off = 32; off > 0; off >>= 1) {
        s1 += __shfl_down(s1, off, 64);
        s2 += __shfl_down(s2, off, 64);
        sr += __shfl_down(sr, off, 64);
    }
    __shared__ float wsr[4];
    if (lane == 0) {
        sq[row] = s1;
        sq[N + row] = s2;
        wsr[wave] = sr;
    }
    __syncthreads();
    if (threadIdx.x == 0)
        accumArr[blockIdx.x] = wsr[0] + wsr[1] + wsr[2] + wsr[3];
}

// ---------------- symmetric f16 MFMA GEMM: upper-tri tile pairs only (by <= bx).
// Writes tile (by,bx) staged+coalesced AND tile (bx,by) transposed-scattered
// (R9 measured scattered == staged). Fused round-1 argmin: row-argmin (rows of tile)
// + col-argmin (rows of the transposed tile) -> full coverage of every row.
#define BM 128
#define BN 128
#define BK 32

__global__ __launch_bounds__(256) void gemm_dist_kernel(const u16* __restrict__ h1,
                                                        const u16* __restrict__ h2,
                                                        const float* __restrict__ sqn,
                                                        float* __restrict__ dist1,
                                                        float* __restrict__ dist2,
                                                        u64* __restrict__ compBest) {
    const int m = blockIdx.z;
    const u16* H = m ? h2 : h1;
    const float* SQ = sqn + (size_t)m * N;
    float* dist = m ? dist2 : dist1;
    u64* cb = compBest + (size_t)m * N;

    // triangular decode: blockIdx.x -> (by <= bx)
    int rem = blockIdx.x, by = 0;
    while (rem >= NT - by) { rem -= NT - by; ++by; }
    const int bx = by + rem;

    __shared__ u16 SH[2 * BM * BK];   // K-loop: Ah|Bh ; epilogue: 4x 16x64 f32 slabs
    u16* Ah = SH;
    u16* Bh = SH + BM * BK;

    const int tid = threadIdx.x;
    const int wave = tid >> 6, lane = tid & 63;
    const int wm = wave >> 1, wn = wave & 1;
    const int row0 = by * BM, col0 = bx * BN;

    floatx4 acc[4][4] = {};

    const int srow = lane >> 2;        // 4 lanes per row, 64B contiguous
    const int scol = (lane & 3) * 8;   // monotone k-chunks

    for (int k0 = 0; k0 < D; k0 += BK) {
        __syncthreads();
#pragma unroll
        for (int i = 0; i < 2; ++i) {
            const int rb = wave * 32 + i * 16;
            const u16* ga = H + (size_t)(row0 + rb + srow) * D + k0 + scol;
            const u16* gb = H + (size_t)(col0 + rb + srow) * D + k0 + scol;
            __builtin_amdgcn_global_load_lds(
                (const __attribute__((address_space(1))) unsigned int*)ga,
                (__attribute__((address_space(3))) unsigned int*)&Ah[rb * BK], 16, 0, 0);
            __builtin_amdgcn_global_load_lds(
                (const __attribute__((address_space(1))) unsigned int*)gb,
                (__attribute__((address_space(3))) unsigned int*)&Bh[rb * BK], 16, 0, 0);
        }
        __syncthreads();

        const int fo = (lane >> 4) * 8;
        const int fm = lane & 15;
        f16x8 a8[4], b8[4];
#pragma unroll
        for (int s = 0; s < 4; ++s) {
            a8[s] = *(const f16x8*)&Ah[(wm * 64 + s * 16 + fm) * BK + fo];
            b8[s] = *(const f16x8*)&Bh[(wn * 64 + s * 16 + fm) * BK + fo];
        }
#pragma unroll
        for (int i = 0; i < 4; ++i)
#pragma unroll
            for (int j = 0; j < 4; ++j)
                acc[i][j] = __builtin_amdgcn_mfma_f32_16x16x32_f16(a8[i], b8[j], acc[i][j], 0, 0, 0);
    }

    __syncthreads();
    float* Cs = (float*)SH + wave * 1024;

    const int lr = lane & 15;
    const int lq = lane >> 4;
    const bool offdiag = (bx != by);
    float sc[4];
    u64 cpk[4] = {~0ull, ~0ull, ~0ull, ~0ull};   // per-ns column argmin accumulators
#pragma unroll
    for (int ns = 0; ns < 4; ++ns) sc[ns] = SQ[col0 + wn * 64 + ns * 16 + lr];
#pragma unroll
    for (int ms = 0; ms < 4; ++ms) {
        const int rb = row0 + wm * 64 + ms * 16 + lq * 4;
        float srow_[4];
#pragma unroll
        for (int r = 0; r < 4; ++r) srow_[r] = SQ[rb + r];
#pragma unroll
        for (int r = 0; r < 4; ++r) {
            const int row = rb + r;
            float dval[4];
#pragma unroll
            for (int ns = 0; ns < 4; ++ns) {
                const int col = col0 + wn * 64 + ns * 16 + lr;
                float d2 = srow_[r] + sc[ns] - 2.0f * acc[ms][ns][r];
                dval[ns] = (row == col) ? BIG : sqrtf(fmaxf(d2, 1e-12f));
                // column argmin accumulation (covers rows of the transposed tile)
                u64 pc = (((u64)__float_as_uint(dval[ns])) << 32) | (unsigned)row;
                cpk[ns] = pc < cpk[ns] ? pc : cpk[ns];
                // transposed scattered store (tile (bx,by))
                if (offdiag) dist[(size_t)col * N + row] = dval[ns];
            }
            float vmin = fminf(fminf(dval[0], dval[1]), fminf(dval[2], dval[3]));
            int nsel = (dval[0] == vmin) ? 0 : (dval[1] == vmin) ? 1 : (dval[2] == vmin) ? 2 : 3;
            u64 pmin = (((u64)__float_as_uint(vmin)) << 32) | (unsigned)(col0 + wn * 64 + nsel * 16 + lr);
#pragma unroll
            for (int msk = 1; msk < 16; msk <<= 1) {
                u64 o = __shfl_xor(pmin, msk, 64);
                pmin = o < pmin ? o : pmin;
            }
            if (lr == 0) atomicMin(&cb[row], pmin);
#pragma unroll
            for (int ns = 0; ns < 4; ++ns)
                Cs[(lq * 4 + r) * 64 + ns * 16 + lr] = dval[ns];
        }
#pragma unroll
        for (int p = 0; p < 4; ++p) {
            float4 v4 = *(float4*)&Cs[p * 256 + lane * 4];
            const int gr = row0 + wm * 64 + ms * 16 + p * 4 + (lane >> 4);
            const int gc = col0 + wn * 64 + (lane & 15) * 4;
            *(float4*)&dist[(size_t)gr * N + gc] = v4;
        }
    }
    // column argmin: reduce across the 4 lq groups (lanes lr+16*lq), then 1 atomic/col
#pragma unroll
    for (int ns = 0; ns < 4; ++ns) {
        u64 p = cpk[ns];
        u64 o = __shfl_xor(p, 16, 64); p = o < p ? o : p;
        o = __shfl_xor(p, 32, 64); p = o < p ? o : p;
        if (lq == 0) atomicMin(&cb[col0 + wn * 64 + ns * 16 + lr], p);
    }
}

// ---------------- merge round 1 + dense relabel + member lists + balanced chunk-task list
__global__ __launch_bounds__(1024) void merge1_kernel(int* __restrict__ comp,
                                                      u64* __restrict__ compBest,
                                                      float* __restrict__ deaths,
                                                      int* __restrict__ cnt,
                                                      int* __restrict__ numComp,
                                                      int* __restrict__ numC1,
                                                      int* __restrict__ memberList,
                                                      int* __restrict__ compStart,
                                                      int* __restrict__ taskOff,
                                                      int* __restrict__ task_c,
                                                      int* __restrict__ task_s0,
                                                      int* __restrict__ task_s1) {
    const int m = blockIdx.x;
    int* cp = comp + (size_t)m * N;
    u64* cb = compBest + (size_t)m * N;
    float* dth = deaths + (size_t)m * N;
    int* mlist = memberList + (size_t)m * N;
    int* cstart = compStart + (size_t)m * (CMAX + 1);
    int* toff = taskOff + (size_t)m * (CMAX + 1);
    int* tc = task_c + (size_t)m * TMAX;
    int* ts0 = task_s0 + (size_t)m * TMAX;
    int* ts1 = task_s1 + (size_t)m * TMAX;
    const int t = threadIdx.x;

    __shared__ int pa[N];
    __shared__ int pb[N];
    __shared__ unsigned flagbits[NW];
    __shared__ int wpc[NW];
    __shared__ int cnts[CMAX];
    __shared__ int cnts2[CMAX];
    __shared__ int done;

    if (t == 0) cnt[m] = 0;
    __syncthreads();

    for (int c = t; c < N; c += 1024) {
        u64 best = cb[c];
        int p = c;
        if (best != ~0ull) {
            int j = (int)(unsigned)best;
            int c2 = cp[j];
            u64 best2 = cb[c2];
            int j2 = (int)(unsigned)best2;
            bool mutual = (cp[j2] == c);
            if (!(mutual && c < c2)) {
                p = c2;
                int idx = atomicAdd(cnt + m, 1);
                dth[idx] = __uint_as_float((unsigned)(best >> 32));
            }
        }
        pa[c] = p;
    }

    int* A = pa;
    int* B = pb;
    while (true) {
        __syncthreads();
        if (t == 0) done = 1;
        __syncthreads();
        bool ch = false;
        for (int c = t; c < N; c += 1024) {
            int g = A[A[c]];
            B[c] = g;
            ch |= (g != A[c]);
        }
        if (ch) done = 0;
        __syncthreads();
        int* tmp = A; A = B; B = tmp;
        if (done) break;
    }

    for (int w = t; w < NW; w += 1024) flagbits[w] = 0u;
    __syncthreads();
    for (int i = t; i < N; i += 1024)
        atomicOr(&flagbits[A[i] >> 5], 1u << (A[i] & 31));
    __syncthreads();
    if (t < NW) wpc[t] = __popc(flagbits[t]);
    __syncthreads();
    for (int off = 1; off < NW; off <<= 1) {
        int v = 0;
        if (t < NW) v = wpc[t] + ((t >= off) ? wpc[t - off] : 0);
        __syncthreads();
        if (t < NW) wpc[t] = v;
        __syncthreads();
    }
    for (int i = t; i < N; i += 1024) {
        int root = A[i];
        int w = root >> 5, b = root & 31;
        int base = w ? wpc[w - 1] : 0;
        unsigned mask = b ? ((1u << b) - 1u) : 0u;
        cp[i] = base + __popc(flagbits[w] & mask);
    }
    for (int c = t; c < CMAX; c += 1024) cnts[c] = 0;
    __syncthreads();
    for (int i = t; i < N; i += 1024) atomicAdd(&cnts[cp[i]], 1);
    __syncthreads();
    int* S = cnts; int* T_ = cnts2;
    for (int off = 1; off < CMAX; off <<= 1) {
        for (int c = t; c < CMAX; c += 1024)
            T_[c] = S[c] + ((c >= off) ? S[c - off] : 0);
        __syncthreads();
        int* tmp = S; S = T_; T_ = tmp;
    }
    for (int c = t; c <= CMAX; c += 1024) cstart[c] = (c == 0) ? 0 : S[c - 1];
    for (int c = t; c < CMAX; c += 1024) T_[c] = (c == 0) ? 0 : S[c - 1];
    __syncthreads();
    for (int i = t; i < N; i += 1024) {
        int pos = atomicAdd(&T_[cp[i]], 1);
        mlist[pos] = i;
    }
    for (int c = t; c < N; c += 1024) cb[c] = ~0ull;
    __syncthreads();
    int* U = pa; int* V = pb;
    for (int c = t; c < CMAX; c += 1024) {
        int mcnt = S[c] - (c ? S[c - 1] : 0);
        U[c] = (mcnt + CH - 1) / CH;
    }
    __syncthreads();
    for (int off = 1; off < CMAX; off <<= 1) {
        for (int c = t; c < CMAX; c += 1024)
            V[c] = U[c] + ((c >= off) ? U[c - off] : 0);
        __syncthreads();
        int* tmp = U; U = V; V = tmp;
    }
    for (int c = t; c <= CMAX; c += 1024) toff[c] = (c == 0) ? 0 : U[c - 1];
    __syncthreads();
    for (int c = t; c < CMAX; c += 1024) {
        int mstart = c ? S[c - 1] : 0;
        int mend = S[c];
        int base = c ? U[c - 1] : 0;
        for (int s0 = mstart, k = 0; s0 < mend; s0 += CH, ++k) {
            tc[base + k] = c;
            ts0[base + k] = s0;
            ts1[base + k] = (s0 + CH < mend) ? (s0 + CH) : mend;
        }
    }
    if (t == 0) {
        int C1 = wpc[NW - 1];
        numC1[m] = C1;
        numComp[m] = C1;
    }
}

// ---------------- level-1 contraction phase A: per-row comp mins, in-place
__global__ __launch_bounds__(256) void rowmin_kernel(float* __restrict__ dist1,
                                                     float* __restrict__ dist2,
                                                     const int* __restrict__ comp) {
    const int m = blockIdx.y;
    float* dist = m ? dist2 : dist1;
    const int* cp = comp + (size_t)m * N;
    const int i = blockIdx.x;
    float* row = dist + (size_t)i * N;
    const float4* row4 = (const float4*)row;
    const int4* cp4 = (const int4*)cp;
    __shared__ unsigned bins[CMAX];
    const int t = threadIdx.x;
    for (int b = t; b < CMAX; b += 256) bins[b] = 0x7f800000u;
    __syncthreads();
#pragma unroll
    for (int k = 0; k < 4; ++k) {
        int q = t + 256 * k;
        float4 v = row4[q];
        int4 cj = cp4[q];
        atomicMin(&bins[cj.x], __float_as_uint(v.x));
        atomicMin(&bins[cj.y], __float_as_uint(v.y));
        atomicMin(&bins[cj.z], __float_as_uint(v.z));
        atomicMin(&bins[cj.w], __float_as_uint(v.w));
    }
    __syncthreads();
    for (int b = t; b < CMAX; b += 256) row[b] = __uint_as_float(bins[b]);
}

// ---------------- colmin phase A: balanced chunk tasks; partials into dead cols [CMAX,N)
__global__ __launch_bounds__(256) void colmin_a_kernel(float* __restrict__ dist1,
                                                       float* __restrict__ dist2,
                                                       const int* __restrict__ memberList,
                                                       const int* __restrict__ taskOff,
                                                       const int* __restrict__ task_c,
                                                       const int* __restrict__ task_s0,
                                                       const int* __restrict__ task_s1) {
    const int m = blockIdx.z;
    const int tk = blockIdx.x;
    const int* toff = taskOff + (size_t)m * (CMAX + 1);
    if (tk >= toff[CMAX]) return;
    float* dist = m ? dist2 : dist1;
    const int* mlist = memberList + (size_t)m * N;
    const int s0 = task_s0[(size_t)m * TMAX + tk];
    const int s1 = task_s1[(size_t)m * TMAX + tk];
    const int b = blockIdx.y * 256 + threadIdx.x;
    float mn = BIG;
    for (int k = s0; k < s1; ++k) {
        const int i = mlist[k];
        mn = fminf(mn, dist[(size_t)i * N + b]);
    }
    dist[(size_t)tk * N + CMAX + b] = mn;
}

// ---------------- colmin phase B + FUSED round-2 scan
__global__ __launch_bounds__(256) void colmin_b_kernel(const float* __restrict__ dist1,
                                                       const float* __restrict__ dist2,
                                                       const int* __restrict__ taskOff,
                                                       const int* __restrict__ numC1,
                                                       float* __restrict__ distc,
                                                       u64* __restrict__ compBest) {
    const int m = blockIdx.z;
    const int c = blockIdx.x;
    const int C1 = numC1[m];
    if (c >= C1) return;
    const float* dist = m ? dist2 : dist1;
    const int* toff = taskOff + (size_t)m * (CMAX + 1);
    const int t0 = toff[c], t1 = toff[c + 1];
    const int b = blockIdx.y * 256 + threadIdx.x;
    float mn = BIG;
    for (int tk = t0; tk < t1; ++tk)
        mn = fminf(mn, dist[(size_t)tk * N + CMAX + b]);
    distc[((size_t)m * CMAX + c) * CMAX + b] = (b == c) ? BIG : mn;
    u64 p = (b == c || C1 <= 1) ? ~0ull : ((((u64)__float_as_uint(mn)) << 32) | (unsigned)b);
#pragma unroll
    for (int off = 32; off > 0; off >>= 1) {
        u64 o = __shfl_down(p, off, 64);
        p = o < p ? o : p;
    }
    if ((threadIdx.x & 63) == 0) atomicMin(&compBest[(size_t)m * N + c], p);
}

// ---------------- merge round 2 + dense relabel to level-2 + member lists
__global__ __launch_bounds__(1024) void merge2_kernel(int* __restrict__ comp_c,
                                                      u64* __restrict__ compBest,
                                                      float* __restrict__ deaths,
                                                      int* __restrict__ cnt,
                                                      int* __restrict__ numComp,
                                                      const int* __restrict__ numC1,
                                                      int* __restrict__ numC2,
                                                      int* __restrict__ memberList2,
                                                      int* __restrict__ compStart2,
                                                      int* __restrict__ comp_c2) {
    const int m = blockIdx.x;
    const int t = threadIdx.x;
    const int C1 = numC1[m];
    int* cc2i = comp_c2 + (size_t)m * CMAX2;
    for (int c = t; c < CMAX2; c += 1024) cc2i[c] = c;
    int* cs = compStart2 + (size_t)m * (CMAX2 + 1);
    if (numComp[m] <= 1) {
        for (int c = t; c <= CMAX2; c += 1024) cs[c] = 0;
        if (t == 0) numC2[m] = numComp[m];
        return;
    }
    int* cc = comp_c + (size_t)m * CMAX;
    u64* cb = compBest + (size_t)m * N;
    float* dth = deaths + (size_t)m * N;
    int* ml = memberList2 + (size_t)m * CMAX;

    __shared__ int pa[CMAX];
    __shared__ int pb[CMAX];
    __shared__ unsigned flagbits[CMAX / 32];
    __shared__ int wpc[CMAX / 32];
    __shared__ int cnts[CMAX2];
    __shared__ int cnts2s[CMAX2];
    __shared__ int done;

    for (int c = t; c < C1; c += 1024) {
        u64 best = cb[c];
        int p = c;
        if (best != ~0ull) {
            int j = (int)(unsigned)best;
            int c2 = cc[j];
            u64 best2 = cb[c2];
            int j2 = (int)(unsigned)best2;
            bool mutual = (cc[j2] == c);
            if (!(mutual && c < c2)) {
                p = c2;
                int idx = atomicAdd(cnt + m, 1);
                dth[idx] = __uint_as_float((unsigned)(best >> 32));
            }
        }
        pa[c] = p;
    }

    int* A = pa;
    int* B = pb;
    while (true) {
        __syncthreads();
        if (t == 0) done = 1;
        __syncthreads();
        bool ch = false;
        for (int c = t; c < C1; c += 1024) {
            int g = A[A[c]];
            B[c] = g;
            ch |= (g != A[c]);
        }
        if (ch) done = 0;
        __syncthreads();
        int* tmp = A; A = B; B = tmp;
        if (done) break;
    }

    for (int w = t; w < CMAX / 32; w += 1024) flagbits[w] = 0u;
    __syncthreads();
    for (int j = t; j < C1; j += 1024)
        atomicOr(&flagbits[A[j] >> 5], 1u << (A[j] & 31));
    __syncthreads();
    if (t < CMAX / 32) wpc[t] = __popc(flagbits[t]);
    __syncthreads();
    for (int off = 1; off < CMAX / 32; off <<= 1) {
        int v = 0;
        if (t < CMAX / 32) v = wpc[t] + ((t >= off) ? wpc[t - off] : 0);
        __syncthreads();
        if (t < CMAX / 32) wpc[t] = v;
        __syncthreads();
    }
    for (int j = t; j < C1; j += 1024) {
        int root = A[j];
        int w = root >> 5, b = root & 31;
        int base = w ? wpc[w - 1] : 0;
        unsigned mask = b ? ((1u << b) - 1u) : 0u;
        cc[j] = base + __popc(flagbits[w] & mask);
    }
    for (int c = t; c < CMAX2; c += 1024) cnts[c] = 0;
    __syncthreads();
    for (int j = t; j < C1; j += 1024) atomicAdd(&cnts[cc[j]], 1);
    __syncthreads();
    int* S = cnts; int* T_ = cnts2s;
    for (int off = 1; off < CMAX2; off <<= 1) {
        for (int c = t; c < CMAX2; c += 1024)
            T_[c] = S[c] + ((c >= off) ? S[c - off] : 0);
        __syncthreads();
        int* tmp = S; S = T_; T_ = tmp;
    }
    for (int c = t; c <= CMAX2; c += 1024) cs[c] = (c == 0) ? 0 : S[c - 1];
    for (int c = t; c < CMAX2; c += 1024) T_[c] = (c == 0) ? 0 : S[c - 1];
    __syncthreads();
    for (int j = t; j < C1; j += 1024) {
        int pos = atomicAdd(&T_[cc[j]], 1);
        ml[pos] = j;
    }
    for (int c = t; c < C1; c += 1024) cb[c] = ~0ull;
    if (t == 0) {
        int C2 = wpc[CMAX / 32 - 1];
        numC2[m] = C2;
        numComp[m] = C2;
    }
}

// ---------------- level-2 contraction phase A
__global__ __launch_bounds__(256) void rowmin2_kernel(float* __restrict__ distc,
                                                      const int* __restrict__ comp_c,
                                                      const int* __restrict__ numC1) {
    const int m = blockIdx.y;
    const int C1 = numC1[m];
    const int r = blockIdx.x;
    if (r >= C1) return;
    const int* cc = comp_c + (size_t)m * CMAX;
    float* row = distc + ((size_t)m * CMAX + r) * CMAX;
    __shared__ unsigned bins[CMAX2];
    const int t = threadIdx.x;
    for (int b = t; b < CMAX2; b += 256) bins[b] = 0x7f800000u;
    __syncthreads();
    for (int j = t; j < C1; j += 256) {
        float v = row[j];
        atomicMin(&bins[cc[j]], __float_as_uint(v));
    }
    __syncthreads();
    for (int b = t; b < CMAX2; b += 256) row[b] = __uint_as_float(bins[b]);
}

// ---------------- level-2 contraction phase B -> distc2
__global__ __launch_bounds__(256) void colmin2_kernel(const float* __restrict__ distc,
                                                      const int* __restrict__ memberList2,
                                                      const int* __restrict__ compStart2,
                                                      const int* __restrict__ numC2,
                                                      float* __restrict__ distc2) {
    const int m = blockIdx.z;
    const int c = blockIdx.x;
    const int C2 = numC2[m];
    if (c >= C2) return;
    const int* ml = memberList2 + (size_t)m * CMAX;
    const int* cs = compStart2 + (size_t)m * (CMAX2 + 1);
    const int b = blockIdx.y * 256 + threadIdx.x;
    const int s0 = cs[c], s1 = cs[c + 1];
    float mn = BIG;
    for (int k = s0; k < s1; ++k) {
        const int r = ml[k];
        float v = distc[((size_t)m * CMAX + r) * CMAX + b];
        mn = fminf(mn, v);
    }
    distc2[((size_t)m * CMAX2 + c) * CMAX2 + b] = (b == c) ? BIG : mn;
}

// ---------------- finish: ALL rounds >= 3, one block per matrix, LDS state, early exit
__global__ __launch_bounds__(1024) void finish_kernel(const float* __restrict__ distc2,
                                                      const int* __restrict__ comp_c2,
                                                      float* __restrict__ deaths,
                                                      int* __restrict__ cnt,
                                                      int* __restrict__ numComp,
                                                      const int* __restrict__ numC2) {
    const int m = blockIdx.x;
    int nc = numComp[m];
    if (nc <= 1) return;
    const int C2 = numC2[m];
    const float* Dm = distc2 + (size_t)m * CMAX2 * CMAX2;
    float* dth = deaths + (size_t)m * N;
    const int t = threadIdx.x;
    const int wave = t >> 6, lane = t & 63;
    __shared__ int comp[CMAX2];
    __shared__ u64 cb[CMAX2];
    __shared__ int pa[CMAX2];
    __shared__ int pb[CMAX2];
    __shared__ unsigned flags[CMAX2 / 32];
    __shared__ int done, ncs;

    for (int c = t; c < C2; c += 1024) {
        comp[c] = comp_c2[(size_t)m * CMAX2 + c];
        cb[c] = ~0ull;
    }
    __syncthreads();

    for (int round = 0; round < 10 && nc > 1; ++round) {
        for (int r = wave; r < C2; r += 16) {
            const int myc = comp[r];
            const float* row = Dm + (size_t)r * CMAX2;
            u64 best = ~0ull;
            for (int j = lane; j < C2; j += 64) {
                if (comp[j] != myc) {
                    u64 p = (((u64)__float_as_uint(row[j])) << 32) | (unsigned)j;
                    best = p < best ? p : best;
                }
            }
#pragma unroll
            for (int off = 32; off > 0; off >>= 1) {
                u64 o = __shfl_down(best, off, 64);
                best = o < best ? o : best;
            }
            if (lane == 0) atomicMin(&cb[myc], best);
        }
        __syncthreads();
        for (int c = t; c < C2; c += 1024) {
            u64 best = cb[c];
            int p = c;
            if (best != ~0ull) {
                int j = (int)(unsigned)best;
                int c2 = comp[j];
                u64 best2 = cb[c2];
                int j2 = (int)(unsigned)best2;
                bool mutual = (comp[j2] == c);
                if (!(mutual && c < c2)) {
                    p = c2;
                    int idx = atomicAdd(cnt + m, 1);
                    dth[idx] = __uint_as_float((unsigned)(best >> 32));
                }
            }
            pa[c] = p;
        }
        int* A = pa; int* B = pb;
        while (true) {
            __syncthreads();
            if (t == 0) done = 1;
            __syncthreads();
            bool ch = false;
            for (int c = t; c < C2; c += 1024) {
                int g = A[A[c]];
                B[c] = g;
                ch |= (g != A[c]);
            }
            if (ch) done = 0;
            __syncthreads();
            int* tmp = A; A = B; B = tmp;
            if (done) break;
        }
        for (int w = t; w < CMAX2 / 32; w += 1024) flags[w] = 0u;
        __syncthreads();
        for (int j = t; j < C2; j += 1024) {
            int root = A[comp[j]];
            comp[j] = root;
            atomicOr(&flags[root >> 5], 1u << (root & 31));
        }
        for (int c = t; c < C2; c += 1024) cb[c] = ~0ull;
        __syncthreads();
        if (t == 0) {
            int s = 0;
            for (int w = 0; w < CMAX2 / 32; ++w) s += __popc(flags[w]);
            ncs = s;
        }
        __syncthreads();
        nc = ncs;
    }
    if (t == 0) numComp[m] = nc;
}

// ---------------- bitonic sort of 4096 (4095 deaths + BIG pad)
__global__ __launch_bounds__(1024) void sort_kernel(float* __restrict__ deaths1,
                                                    float* __restrict__ deaths2) {
    float* deaths = (blockIdx.x == 0) ? deaths1 : deaths2;
    __shared__ float s[N];
    const int tid = threadIdx.x;
    for (int i = tid; i < N; i += 1024)
        s[i] = (i < N - 1) ? deaths[i] : BIG;
    __syncthreads();
    for (int k = 2; k <= N; k <<= 1) {
        for (int jj = k >> 1; jj > 0; jj >>= 1) {
            for (int t = tid; t < N; t += 1024) {
                int ixj = t ^ jj;
                if (ixj > t) {
                    float a = s[t], b = s[ixj];
                    bool up = ((t & k) == 0);
                    bool sw = up ? (a > b) : (a < b);
                    if (sw) { s[t] = b; s[ixj] = a; }
                }
            }
            __syncthreads();
        }
    }
    for (int i = tid; i < N; i += 1024) deaths[i] = s[i];
}

// ---------------- final: W1 + L2 (sums accumArr partials)
__global__ __launch_bounds__(1024) void final_kernel(const float* __restrict__ s1,
                                                     const float* __restrict__ s2,
                                                     const float* __restrict__ accumArr,
                                                     float* __restrict__ out) {
    __shared__ float wsum[16];
    __shared__ float rsum[16];
    float sum = 0.f;
    for (int i = threadIdx.x; i < N - 1; i += 1024) {
        float a = s1[i], b = s2[i];
        sum += fminf(fabsf(a - b), 0.5f * (a + b));
    }
    float ra = accumArr[threadIdx.x];
#pragma unroll
    for (int off = 32; off > 0; off >>= 1) {
        sum += __shfl_down(sum, off, 64);
        ra += __shfl_down(ra, off, 64);
    }
    int lane = threadIdx.x & 63, wid = threadIdx.x >> 6;
    if (lane == 0) { wsum[wid] = sum; rsum[wid] = ra; }
    __syncthreads();
    if (threadIdx.x == 0) {
        float tot = 0.f, rt = 0.f;
        for (int k = 0; k < 16; ++k) { tot += wsum[k]; rt += rsum[k]; }
        out[0] = rt * (1.0f / ((float)N * (float)D)) + tot;
    }
}

extern "C" void kernel_launch(void* const* d_in, const int* in_sizes, int n_in,
                              void* d_out, int out_size, void* d_ws, size_t ws_size,
                              hipStream_t stream) {
    const float* x1 = (const float*)d_in[0];
    const float* x2 = (const float*)d_in[1];
    float* out = (float*)d_out;
    float* ws = (float*)d_ws;

    const size_t nn = (size_t)N * N;
    const size_t cc2 = (size_t)CMAX * CMAX;

    float* dist1 = ws;
    float* dist2 = ws + nn;
    float* distc = ws + 2 * nn;
    u16* h1 = (u16*)distc;                 // alias: dead before colmin_b writes distc
    u16* h2 = h1 + (size_t)N * D;
    u64* compBest = (u64*)(distc + 2 * cc2);
    int* comp      = (int*)(compBest + 2 * N);
    int* comp_c    = comp + 2 * N;
    int* memberList = comp_c + 2 * CMAX;
    int* compStart  = memberList + 2 * N;
    float* deaths  = (float*)(compStart + 2 * (CMAX + 1));
    int* cnt       = (int*)(deaths + 2 * N);
    int* numComp   = cnt + 2;
    int* numC1     = numComp + 2;
    float* accum   = (float*)(numC1 + 2);
    float* sq      = accum + 2;
    int* taskOff   = (int*)(sq + 2 * N);
    int* task_c    = taskOff + 2 * (CMAX + 1);
    int* task_s0   = task_c + 2 * TMAX;
    int* task_s1   = task_s0 + 2 * TMAX;
    float* accumArr = (float*)(task_s1 + 2 * TMAX);   // 1024 floats
    // level-2 buffers alias dist1 (dead after colmin) — initialized in merge2_kernel,
    // NEVER earlier (R7 crash: init before gemm overwrote them -> OOB)
    float* distc2  = dist1;
    int* comp_c2   = (int*)(distc2 + 2 * (size_t)CMAX2 * CMAX2);
    int* memberList2 = comp_c2 + 2 * CMAX2;
    int* compStart2  = memberList2 + 2 * CMAX;
    int* numC2       = compStart2 + 2 * (CMAX2 + 1);

    prep_kernel<<<N / 4, 256, 0, stream>>>(x1, x2, h1, h2, sq, accumArr, comp, compBest, comp_c);
    gemm_dist_kernel<<<dim3(NTRI, 1, 2), 256, 0, stream>>>(h1, h2, sq, dist1, dist2, compBest);
    merge1_kernel<<<2, 1024, 0, stream>>>(comp, compBest, deaths, cnt, numComp, numC1,
                                          memberList, compStart, taskOff, task_c, task_s0, task_s1);
    rowmin_kernel<<<dim3(N, 2), 256, 0, stream>>>(dist1, dist2, comp);
    colmin_a_kernel<<<dim3(TMAX, CMAX / 256, 2), 256, 0, stream>>>(dist1, dist2, memberList,
                                                                   taskOff, task_c, task_s0, task_s1);
    colmin_b_kernel<<<dim3(CMAX, CMAX / 256, 2), 256, 0, stream>>>(dist1, dist2, taskOff, numC1,
                                                                   distc, compBest);
    merge2_kernel<<<2, 1024, 0, stream>>>(comp_c, compBest, deaths, cnt, numComp, numC1, numC2,
                                          memberList2, compStart2, comp_c2);
    rowmin2_kernel<<<dim3(CMAX, 2), 256, 0, stream>>>(distc, comp_c, numC1);
    colmin2_kernel<<<dim3(CMAX2, CMAX2 / 256, 2), 256, 0, stream>>>(distc, memberList2, compStart2, numC2, distc2);
    finish_kernel<<<2, 1024, 0, stream>>>(distc2, comp_c2, deaths, cnt, numComp, numC2);
    sort_kernel<<<2, 1024, 0, stream>>>(deaths, deaths + N);
    final_kernel<<<1, 1024, 0, stream>>>(deaths, deaths + N, accumArr, out);
}

// Round 15
// 315.279 us; speedup vs baseline: 1.0422x; 1.0422x over previous
//
#include <hip/hip_runtime.h>

#define N 4096
#define D 512
#define BIG 1e30f
#define CMAX 2048
#define CMAX2 1024
#define NW (N / 32)
#define CH 16            // member rows per colmin task
#define TMAX 2304        // max tasks = CMAX + N/CH

typedef unsigned long long u64;
typedef unsigned short u16;
typedef _Float16 f16x8 __attribute__((ext_vector_type(8)));
typedef float floatx4 __attribute__((ext_vector_type(4)));

// ---------------- fused prep: f32->f16 convert + row sq-norms + repr partial + ALL init
__global__ __launch_bounds__(256) void prep_kernel(const float* __restrict__ x1,
                                                   const float* __restrict__ x2,
                                                   u16* __restrict__ h1,
                                                   u16* __restrict__ h2,
                                                   float* __restrict__ sq,
                                                   float* __restrict__ accumArr,
                                                   int* __restrict__ comp,
                                                   u64* __restrict__ compBest,
                                                   int* __restrict__ comp_c) {
    const int tid = blockIdx.x * 256 + threadIdx.x;
    if (tid < 2 * N) {
        comp[tid] = tid & (N - 1);
        compBest[tid] = ~0ull;
    }
    if (tid < 2 * CMAX) comp_c[tid] = tid & (CMAX - 1);

    const int wave = threadIdx.x >> 6, lane = threadIdx.x & 63;
    const int row = blockIdx.x * 4 + wave;
    const float4* r1 = (const float4*)(x1 + (size_t)row * D);
    const float4* r2 = (const float4*)(x2 + (size_t)row * D);
    float4 a0 = r1[lane * 2], a1 = r1[lane * 2 + 1];
    float4 b0 = r2[lane * 2], b1 = r2[lane * 2 + 1];
    ushort4* o1 = (ushort4*)(h1 + (size_t)row * D + lane * 8);
    ushort4* o2 = (ushort4*)(h2 + (size_t)row * D + lane * 8);
    o1[0] = make_ushort4(__builtin_bit_cast(u16, (_Float16)a0.x), __builtin_bit_cast(u16, (_Float16)a0.y),
                         __builtin_bit_cast(u16, (_Float16)a0.z), __builtin_bit_cast(u16, (_Float16)a0.w));
    o1[1] = make_ushort4(__builtin_bit_cast(u16, (_Float16)a1.x), __builtin_bit_cast(u16, (_Float16)a1.y),
                         __builtin_bit_cast(u16, (_Float16)a1.z), __builtin_bit_cast(u16, (_Float16)a1.w));
    o2[0] = make_ushort4(__builtin_bit_cast(u16, (_Float16)b0.x), __builtin_bit_cast(u16, (_Float16)b0.y),
                         __builtin_bit_cast(u16, (_Float16)b0.z), __builtin_bit_cast(u16, (_Float16)b0.w));
    o2[1] = make_ushort4(__builtin_bit_cast(u16, (_Float16)b1.x), __builtin_bit_cast(u16, (_Float16)b1.y),
                         __builtin_bit_cast(u16, (_Float16)b1.z), __builtin_bit_cast(u16, (_Float16)b1.w));
    float s1 = 0.f, s2 = 0.f, sr = 0.f;
    float av[8] = {a0.x, a0.y, a0.z, a0.w, a1.x, a1.y, a1.z, a1.w};
    float bv[8] = {b0.x, b0.y, b0.z, b0.w, b1.x, b1.y, b1.z, b1.w};
#pragma unroll
    for (int e = 0; e < 8; ++e) {
        s1 = fmaf(av[e], av[e], s1);
        s2 = fmaf(bv[e], bv[e], s2);
        float d = av[e] - bv[e];
        sr = fmaf(d, d, sr);
    }
#pragma unroll
    for (int off = 32; off > 0; off >>= 1) {
        s1 += __shfl_down(s1, off, 64);
        s2 += __shfl_down(s2, off, 64);
        sr += __shfl_down(sr, off, 64);
    }
    __shared__ float wsr[4];
    if (lane == 0) {
        sq[row] = s1;
        sq[N + row] = s2;
        wsr[wave] = sr;
    }
    __syncthreads();
    if (threadIdx.x == 0)
        accumArr[blockIdx.x] = wsr[0] + wsr[1] + wsr[2] + wsr[3];
}

// ---------------- single-pass f16 MFMA GEMM + dist epilogue + fused round-1 row argmin
// R13 config — measured best (85-105 us band). R11/R12 LDS swizzles and R14 symmetric
// transposed-scatter all regressed; full-tile + staged coalesced stores is the keeper.
#define BM 128
#define BN 128
#define BK 32

__global__ __launch_bounds__(256) void gemm_dist_kernel(const u16* __restrict__ h1,
                                                        const u16* __restrict__ h2,
                                                        const float* __restrict__ sqn,
                                                        float* __restrict__ dist1,
                                                        float* __restrict__ dist2,
                                                        u64* __restrict__ compBest) {
    const int m = blockIdx.z;
    const u16* H = m ? h2 : h1;
    const float* SQ = sqn + (size_t)m * N;
    float* dist = m ? dist2 : dist1;
    u64* cb = compBest + (size_t)m * N;

    __shared__ u16 SH[2 * BM * BK];   // K-loop: Ah|Bh ; epilogue: 4x 16x64 f32 slabs
    u16* Ah = SH;
    u16* Bh = SH + BM * BK;

    const int tid = threadIdx.x;
    const int wave = tid >> 6, lane = tid & 63;
    const int wm = wave >> 1, wn = wave & 1;
    const int row0 = blockIdx.y * BM, col0 = blockIdx.x * BN;

    floatx4 acc[4][4] = {};

    const int srow = lane >> 2;        // 4 lanes per row, 64B contiguous
    const int scol = (lane & 3) * 8;   // monotone k-chunks

    for (int k0 = 0; k0 < D; k0 += BK) {
        __syncthreads();
#pragma unroll
        for (int i = 0; i < 2; ++i) {
            const int rb = wave * 32 + i * 16;
            const u16* ga = H + (size_t)(row0 + rb + srow) * D + k0 + scol;
            const u16* gb = H + (size_t)(col0 + rb + srow) * D + k0 + scol;
            __builtin_amdgcn_global_load_lds(
                (const __attribute__((address_space(1))) unsigned int*)ga,
                (__attribute__((address_space(3))) unsigned int*)&Ah[rb * BK], 16, 0, 0);
            __builtin_amdgcn_global_load_lds(
                (const __attribute__((address_space(1))) unsigned int*)gb,
                (__attribute__((address_space(3))) unsigned int*)&Bh[rb * BK], 16, 0, 0);
        }
        __syncthreads();

        const int fo = (lane >> 4) * 8;
        const int fm = lane & 15;
        f16x8 a8[4], b8[4];
#pragma unroll
        for (int s = 0; s < 4; ++s) {
            a8[s] = *(const f16x8*)&Ah[(wm * 64 + s * 16 + fm) * BK + fo];
            b8[s] = *(const f16x8*)&Bh[(wn * 64 + s * 16 + fm) * BK + fo];
        }
#pragma unroll
        for (int i = 0; i < 4; ++i)
#pragma unroll
            for (int j = 0; j < 4; ++j)
                acc[i][j] = __builtin_amdgcn_mfma_f32_16x16x32_f16(a8[i], b8[j], acc[i][j], 0, 0, 0);
    }

    __syncthreads();
    float* Cs = (float*)SH + wave * 1024;

    const int lr = lane & 15;
    const int lq = lane >> 4;
    float sc[4];
#pragma unroll
    for (int ns = 0; ns < 4; ++ns) sc[ns] = SQ[col0 + wn * 64 + ns * 16 + lr];
#pragma unroll
    for (int ms = 0; ms < 4; ++ms) {
        const int rb = row0 + wm * 64 + ms * 16 + lq * 4;
        float srow_[4];
#pragma unroll
        for (int r = 0; r < 4; ++r) srow_[r] = SQ[rb + r];
#pragma unroll
        for (int r = 0; r < 4; ++r) {
            const int row = rb + r;
            float dval[4];
#pragma unroll
            for (int ns = 0; ns < 4; ++ns) {
                const int col = col0 + wn * 64 + ns * 16 + lr;
                float d2 = srow_[r] + sc[ns] - 2.0f * acc[ms][ns][r];
                dval[ns] = (row == col) ? BIG : sqrtf(fmaxf(d2, 1e-12f));
            }
            float vmin = fminf(fminf(dval[0], dval[1]), fminf(dval[2], dval[3]));
            int nsel = (dval[0] == vmin) ? 0 : (dval[1] == vmin) ? 1 : (dval[2] == vmin) ? 2 : 3;
            u64 pmin = (((u64)__float_as_uint(vmin)) << 32) | (unsigned)(col0 + wn * 64 + nsel * 16 + lr);
#pragma unroll
            for (int msk = 1; msk < 16; msk <<= 1) {
                u64 o = __shfl_xor(pmin, msk, 64);
                pmin = o < pmin ? o : pmin;
            }
            if (lr == 0) atomicMin(&cb[row], pmin);
#pragma unroll
            for (int ns = 0; ns < 4; ++ns)
                Cs[(lq * 4 + r) * 64 + ns * 16 + lr] = dval[ns];
        }
#pragma unroll
        for (int p = 0; p < 4; ++p) {
            float4 v4 = *(float4*)&Cs[p * 256 + lane * 4];
            const int gr = row0 + wm * 64 + ms * 16 + p * 4 + (lane >> 4);
            const int gc = col0 + wn * 64 + (lane & 15) * 4;
            *(float4*)&dist[(size_t)gr * N + gc] = v4;
        }
    }
}

// ---------------- merge round 1 + dense relabel + member lists + balanced chunk-task list
__global__ __launch_bounds__(1024) void merge1_kernel(int* __restrict__ comp,
                                                      u64* __restrict__ compBest,
                                                      float* __restrict__ deaths,
                                                      int* __restrict__ cnt,
                                                      int* __restrict__ numComp,
                                                      int* __restrict__ numC1,
                                                      int* __restrict__ memberList,
                                                      int* __restrict__ compStart,
                                                      int* __restrict__ taskOff,
                                                      int* __restrict__ task_c,
                                                      int* __restrict__ task_s0,
                                                      int* __restrict__ task_s1) {
    const int m = blockIdx.x;
    int* cp = comp + (size_t)m * N;
    u64* cb = compBest + (size_t)m * N;
    float* dth = deaths + (size_t)m * N;
    int* mlist = memberList + (size_t)m * N;
    int* cstart = compStart + (size_t)m * (CMAX + 1);
    int* toff = taskOff + (size_t)m * (CMAX + 1);
    int* tc = task_c + (size_t)m * TMAX;
    int* ts0 = task_s0 + (size_t)m * TMAX;
    int* ts1 = task_s1 + (size_t)m * TMAX;
    const int t = threadIdx.x;

    __shared__ int pa[N];
    __shared__ int pb[N];
    __shared__ unsigned flagbits[NW];
    __shared__ int wpc[NW];
    __shared__ int cnts[CMAX];
    __shared__ int cnts2[CMAX];
    __shared__ int done;

    if (t == 0) cnt[m] = 0;
    __syncthreads();

    for (int c = t; c < N; c += 1024) {
        u64 best = cb[c];
        int p = c;
        if (best != ~0ull) {
            int j = (int)(unsigned)best;
            int c2 = cp[j];
            u64 best2 = cb[c2];
            int j2 = (int)(unsigned)best2;
            bool mutual = (cp[j2] == c);
            if (!(mutual && c < c2)) {
                p = c2;
                int idx = atomicAdd(cnt + m, 1);
                dth[idx] = __uint_as_float((unsigned)(best >> 32));
            }
        }
        pa[c] = p;
    }

    int* A = pa;
    int* B = pb;
    while (true) {
        __syncthreads();
        if (t == 0) done = 1;
        __syncthreads();
        bool ch = false;
        for (int c = t; c < N; c += 1024) {
            int g = A[A[c]];
            B[c] = g;
            ch |= (g != A[c]);
        }
        if (ch) done = 0;
        __syncthreads();
        int* tmp = A; A = B; B = tmp;
        if (done) break;
    }

    for (int w = t; w < NW; w += 1024) flagbits[w] = 0u;
    __syncthreads();
    for (int i = t; i < N; i += 1024)
        atomicOr(&flagbits[A[i] >> 5], 1u << (A[i] & 31));
    __syncthreads();
    if (t < NW) wpc[t] = __popc(flagbits[t]);
    __syncthreads();
    for (int off = 1; off < NW; off <<= 1) {
        int v = 0;
        if (t < NW) v = wpc[t] + ((t >= off) ? wpc[t - off] : 0);
        __syncthreads();
        if (t < NW) wpc[t] = v;
        __syncthreads();
    }
    for (int i = t; i < N; i += 1024) {
        int root = A[i];
        int w = root >> 5, b = root & 31;
        int base = w ? wpc[w - 1] : 0;
        unsigned mask = b ? ((1u << b) - 1u) : 0u;
        cp[i] = base + __popc(flagbits[w] & mask);
    }
    for (int c = t; c < CMAX; c += 1024) cnts[c] = 0;
    __syncthreads();
    for (int i = t; i < N; i += 1024) atomicAdd(&cnts[cp[i]], 1);
    __syncthreads();
    int* S = cnts; int* T_ = cnts2;
    for (int off = 1; off < CMAX; off <<= 1) {
        for (int c = t; c < CMAX; c += 1024)
            T_[c] = S[c] + ((c >= off) ? S[c - off] : 0);
        __syncthreads();
        int* tmp = S; S = T_; T_ = tmp;
    }
    for (int c = t; c <= CMAX; c += 1024) cstart[c] = (c == 0) ? 0 : S[c - 1];
    for (int c = t; c < CMAX; c += 1024) T_[c] = (c == 0) ? 0 : S[c - 1];
    __syncthreads();
    for (int i = t; i < N; i += 1024) {
        int pos = atomicAdd(&T_[cp[i]], 1);
        mlist[pos] = i;
    }
    for (int c = t; c < N; c += 1024) cb[c] = ~0ull;
    __syncthreads();
    int* U = pa; int* V = pb;
    for (int c = t; c < CMAX; c += 1024) {
        int mcnt = S[c] - (c ? S[c - 1] : 0);
        U[c] = (mcnt + CH - 1) / CH;
    }
    __syncthreads();
    for (int off = 1; off < CMAX; off <<= 1) {
        for (int c = t; c < CMAX; c += 1024)
            V[c] = U[c] + ((c >= off) ? U[c - off] : 0);
        __syncthreads();
        int* tmp = U; U = V; V = tmp;
    }
    for (int c = t; c <= CMAX; c += 1024) toff[c] = (c == 0) ? 0 : U[c - 1];
    __syncthreads();
    for (int c = t; c < CMAX; c += 1024) {
        int mstart = c ? S[c - 1] : 0;
        int mend = S[c];
        int base = c ? U[c - 1] : 0;
        for (int s0 = mstart, k = 0; s0 < mend; s0 += CH, ++k) {
            tc[base + k] = c;
            ts0[base + k] = s0;
            ts1[base + k] = (s0 + CH < mend) ? (s0 + CH) : mend;
        }
    }
    if (t == 0) {
        int C1 = wpc[NW - 1];
        numC1[m] = C1;
        numComp[m] = C1;
    }
}

// ---------------- level-1 contraction phase A: per-row comp mins, in-place
__global__ __launch_bounds__(256) void rowmin_kernel(float* __restrict__ dist1,
                                                     float* __restrict__ dist2,
                                                     const int* __restrict__ comp) {
    const int m = blockIdx.y;
    float* dist = m ? dist2 : dist1;
    const int* cp = comp + (size_t)m * N;
    const int i = blockIdx.x;
    float* row = dist + (size_t)i * N;
    const float4* row4 = (const float4*)row;
    const int4* cp4 = (const int4*)cp;
    __shared__ unsigned bins[CMAX];
    const int t = threadIdx.x;
    for (int b = t; b < CMAX; b += 256) bins[b] = 0x7f800000u;
    __syncthreads();
#pragma unroll
    for (int k = 0; k < 4; ++k) {
        int q = t + 256 * k;
        float4 v = row4[q];
        int4 cj = cp4[q];
        atomicMin(&bins[cj.x], __float_as_uint(v.x));
        atomicMin(&bins[cj.y], __float_as_uint(v.y));
        atomicMin(&bins[cj.z], __float_as_uint(v.z));
        atomicMin(&bins[cj.w], __float_as_uint(v.w));
    }
    __syncthreads();
    for (int b = t; b < CMAX; b += 256) row[b] = __uint_as_float(bins[b]);
}

// ---------------- colmin phase A: balanced chunk tasks; partials into dead cols [CMAX,N)
__global__ __launch_bounds__(256) void colmin_a_kernel(float* __restrict__ dist1,
                                                       float* __restrict__ dist2,
                                                       const int* __restrict__ memberList,
                                                       const int* __restrict__ taskOff,
                                                       const int* __restrict__ task_c,
                                                       const int* __restrict__ task_s0,
                                                       const int* __restrict__ task_s1) {
    const int m = blockIdx.z;
    const int tk = blockIdx.x;
    const int* toff = taskOff + (size_t)m * (CMAX + 1);
    if (tk >= toff[CMAX]) return;
    float* dist = m ? dist2 : dist1;
    const int* mlist = memberList + (size_t)m * N;
    const int s0 = task_s0[(size_t)m * TMAX + tk];
    const int s1 = task_s1[(size_t)m * TMAX + tk];
    const int b = blockIdx.y * 256 + threadIdx.x;
    float mn = BIG;
    for (int k = s0; k < s1; ++k) {
        const int i = mlist[k];
        mn = fminf(mn, dist[(size_t)i * N + b]);
    }
    dist[(size_t)tk * N + CMAX + b] = mn;
}

// ---------------- colmin phase B + FUSED round-2 scan
__global__ __launch_bounds__(256) void colmin_b_kernel(const float* __restrict__ dist1,
                                                       const float* __restrict__ dist2,
                                                       const int* __restrict__ taskOff,
                                                       const int* __restrict__ numC1,
                                                       float* __restrict__ distc,
                                                       u64* __restrict__ compBest) {
    const int m = blockIdx.z;
    const int c = blockIdx.x;
    const int C1 = numC1[m];
    if (c >= C1) return;
    const float* dist = m ? dist2 : dist1;
    const int* toff = taskOff + (size_t)m * (CMAX + 1);
    const int t0 = toff[c], t1 = toff[c + 1];
    const int b = blockIdx.y * 256 + threadIdx.x;
    float mn = BIG;
    for (int tk = t0; tk < t1; ++tk)
        mn = fminf(mn, dist[(size_t)tk * N + CMAX + b]);
    distc[((size_t)m * CMAX + c) * CMAX + b] = (b == c) ? BIG : mn;
    u64 p = (b == c || C1 <= 1) ? ~0ull : ((((u64)__float_as_uint(mn)) << 32) | (unsigned)b);
#pragma unroll
    for (int off = 32; off > 0; off >>= 1) {
        u64 o = __shfl_down(p, off, 64);
        p = o < p ? o : p;
    }
    if ((threadIdx.x & 63) == 0) atomicMin(&compBest[(size_t)m * N + c], p);
}

// ---------------- merge round 2 + dense relabel to level-2 + member lists
__global__ __launch_bounds__(1024) void merge2_kernel(int* __restrict__ comp_c,
                                                      u64* __restrict__ compBest,
                                                      float* __restrict__ deaths,
                                                      int* __restrict__ cnt,
                                                      int* __restrict__ numComp,
                                                      const int* __restrict__ numC1,
                                                      int* __restrict__ numC2,
                                                      int* __restrict__ memberList2,
                                                      int* __restrict__ compStart2,
                                                      int* __restrict__ comp_c2) {
    const int m = blockIdx.x;
    const int t = threadIdx.x;
    const int C1 = numC1[m];
    int* cc2i = comp_c2 + (size_t)m * CMAX2;
    for (int c = t; c < CMAX2; c += 1024) cc2i[c] = c;
    int* cs = compStart2 + (size_t)m * (CMAX2 + 1);
    if (numComp[m] <= 1) {
        for (int c = t; c <= CMAX2; c += 1024) cs[c] = 0;
        if (t == 0) numC2[m] = numComp[m];
        return;
    }
    int* cc = comp_c + (size_t)m * CMAX;
    u64* cb = compBest + (size_t)m * N;
    float* dth = deaths + (size_t)m * N;
    int* ml = memberList2 + (size_t)m * CMAX;

    __shared__ int pa[CMAX];
    __shared__ int pb[CMAX];
    __shared__ unsigned flagbits[CMAX / 32];
    __shared__ int wpc[CMAX / 32];
    __shared__ int cnts[CMAX2];
    __shared__ int cnts2s[CMAX2];
    __shared__ int done;

    for (int c = t; c < C1; c += 1024) {
        u64 best = cb[c];
        int p = c;
        if (best != ~0ull) {
            int j = (int)(unsigned)best;
            int c2 = cc[j];
            u64 best2 = cb[c2];
            int j2 = (int)(unsigned)best2;
            bool mutual = (cc[j2] == c);
            if (!(mutual && c < c2)) {
                p = c2;
                int idx = atomicAdd(cnt + m, 1);
                dth[idx] = __uint_as_float((unsigned)(best >> 32));
            }
        }
        pa[c] = p;
    }

    int* A = pa;
    int* B = pb;
    while (true) {
        __syncthreads();
        if (t == 0) done = 1;
        __syncthreads();
        bool ch = false;
        for (int c = t; c < C1; c += 1024) {
            int g = A[A[c]];
            B[c] = g;
            ch |= (g != A[c]);
        }
        if (ch) done = 0;
        __syncthreads();
        int* tmp = A; A = B; B = tmp;
        if (done) break;
    }

    for (int w = t; w < CMAX / 32; w += 1024) flagbits[w] = 0u;
    __syncthreads();
    for (int j = t; j < C1; j += 1024)
        atomicOr(&flagbits[A[j] >> 5], 1u << (A[j] & 31));
    __syncthreads();
    if (t < CMAX / 32) wpc[t] = __popc(flagbits[t]);
    __syncthreads();
    for (int off = 1; off < CMAX / 32; off <<= 1) {
        int v = 0;
        if (t < CMAX / 32) v = wpc[t] + ((t >= off) ? wpc[t - off] : 0);
        __syncthreads();
        if (t < CMAX / 32) wpc[t] = v;
        __syncthreads();
    }
    for (int j = t; j < C1; j += 1024) {
        int root = A[j];
        int w = root >> 5, b = root & 31;
        int base = w ? wpc[w - 1] : 0;
        unsigned mask = b ? ((1u << b) - 1u) : 0u;
        cc[j] = base + __popc(flagbits[w] & mask);
    }
    for (int c = t; c < CMAX2; c += 1024) cnts[c] = 0;
    __syncthreads();
    for (int j = t; j < C1; j += 1024) atomicAdd(&cnts[cc[j]], 1);
    __syncthreads();
    int* S = cnts; int* T_ = cnts2s;
    for (int off = 1; off < CMAX2; off <<= 1) {
        for (int c = t; c < CMAX2; c += 1024)
            T_[c] = S[c] + ((c >= off) ? S[c - off] : 0);
        __syncthreads();
        int* tmp = S; S = T_; T_ = tmp;
    }
    for (int c = t; c <= CMAX2; c += 1024) cs[c] = (c == 0) ? 0 : S[c - 1];
    for (int c = t; c < CMAX2; c += 1024) T_[c] = (c == 0) ? 0 : S[c - 1];
    __syncthreads();
    for (int j = t; j < C1; j += 1024) {
        int pos = atomicAdd(&T_[cc[j]], 1);
        ml[pos] = j;
    }
    for (int c = t; c < C1; c += 1024) cb[c] = ~0ull;
    if (t == 0) {
        int C2 = wpc[CMAX / 32 - 1];
        numC2[m] = C2;
        numComp[m] = C2;
    }
}

// ---------------- level-2 contraction phase A
__global__ __launch_bounds__(256) void rowmin2_kernel(float* __restrict__ distc,
                                                      const int* __restrict__ comp_c,
                                                      const int* __restrict__ numC1) {
    const int m = blockIdx.y;
    const int C1 = numC1[m];
    const int r = blockIdx.x;
    if (r >= C1) return;
    const int* cc = comp_c + (size_t)m * CMAX;
    float* row = distc + ((size_t)m * CMAX + r) * CMAX;
    __shared__ unsigned bins[CMAX2];
    const int t = threadIdx.x;
    for (int b = t; b < CMAX2; b += 256) bins[b] = 0x7f800000u;
    __syncthreads();
    for (int j = t; j < C1; j += 256) {
        float v = row[j];
        atomicMin(&bins[cc[j]], __float_as_uint(v));
    }
    __syncthreads();
    for (int b = t; b < CMAX2; b += 256) row[b] = __uint_as_float(bins[b]);
}

// ---------------- level-2 contraction phase B -> distc2
__global__ __launch_bounds__(256) void colmin2_kernel(const float* __restrict__ distc,
                                                      const int* __restrict__ memberList2,
                                                      const int* __restrict__ compStart2,
                                                      const int* __restrict__ numC2,
                                                      float* __restrict__ distc2) {
    const int m = blockIdx.z;
    const int c = blockIdx.x;
    const int C2 = numC2[m];
    if (c >= C2) return;
    const int* ml = memberList2 + (size_t)m * CMAX;
    const int* cs = compStart2 + (size_t)m * (CMAX2 + 1);
    const int b = blockIdx.y * 256 + threadIdx.x;
    const int s0 = cs[c], s1 = cs[c + 1];
    float mn = BIG;
    for (int k = s0; k < s1; ++k) {
        const int r = ml[k];
        float v = distc[((size_t)m * CMAX + r) * CMAX + b];
        mn = fminf(mn, v);
    }
    distc2[((size_t)m * CMAX2 + c) * CMAX2 + b] = (b == c) ? BIG : mn;
}

// ---------------- finish: ALL rounds >= 3 + FUSED bitonic sort of this matrix's deaths
__global__ __launch_bounds__(1024) void finish_kernel(const float* __restrict__ distc2,
                                                      const int* __restrict__ comp_c2,
                                                      float* __restrict__ deaths,
                                                      int* __restrict__ cnt,
                                                      int* __restrict__ numComp,
                                                      const int* __restrict__ numC2) {
    const int m = blockIdx.x;
    int nc = numComp[m];
    const int C2 = numC2[m];
    const float* Dm = distc2 + (size_t)m * CMAX2 * CMAX2;
    float* dth = deaths + (size_t)m * N;
    const int t = threadIdx.x;
    const int wave = t >> 6, lane = t & 63;
    __shared__ int comp[CMAX2];
    __shared__ u64 cb[CMAX2];
    __shared__ int pa[CMAX2];
    __shared__ int pb[CMAX2];
    __shared__ unsigned flags[CMAX2 / 32];
    __shared__ int done, ncs;
    __shared__ float s[N];    // sort buffer (36 KB total LDS, fits)

    if (nc > 1) {
        for (int c = t; c < C2; c += 1024) {
            comp[c] = comp_c2[(size_t)m * CMAX2 + c];
            cb[c] = ~0ull;
        }
        __syncthreads();

        for (int round = 0; round < 10 && nc > 1; ++round) {
            for (int r = wave; r < C2; r += 16) {
                const int myc = comp[r];
                const float* row = Dm + (size_t)r * CMAX2;
                u64 best = ~0ull;
                for (int j = lane; j < C2; j += 64) {
                    if (comp[j] != myc) {
                        u64 p = (((u64)__float_as_uint(row[j])) << 32) | (unsigned)j;
                        best = p < best ? p : best;
                    }
                }
#pragma unroll
                for (int off = 32; off > 0; off >>= 1) {
                    u64 o = __shfl_down(best, off, 64);
                    best = o < best ? o : best;
                }
                if (lane == 0) atomicMin(&cb[myc], best);
            }
            __syncthreads();
            for (int c = t; c < C2; c += 1024) {
                u64 best = cb[c];
                int p = c;
                if (best != ~0ull) {
                    int j = (int)(unsigned)best;
                    int c2 = comp[j];
                    u64 best2 = cb[c2];
                    int j2 = (int)(unsigned)best2;
                    bool mutual = (comp[j2] == c);
                    if (!(mutual && c < c2)) {
                        p = c2;
                        int idx = atomicAdd(cnt + m, 1);
                        dth[idx] = __uint_as_float((unsigned)(best >> 32));
                    }
                }
                pa[c] = p;
            }
            int* A = pa; int* B = pb;
            while (true) {
                __syncthreads();
                if (t == 0) done = 1;
                __syncthreads();
                bool ch = false;
                for (int c = t; c < C2; c += 1024) {
                    int g = A[A[c]];
                    B[c] = g;
                    ch |= (g != A[c]);
                }
                if (ch) done = 0;
                __syncthreads();
                int* tmp = A; A = B; B = tmp;
                if (done) break;
            }
            for (int w = t; w < CMAX2 / 32; w += 1024) flags[w] = 0u;
            __syncthreads();
            for (int j = t; j < C2; j += 1024) {
                int root = A[comp[j]];
                comp[j] = root;
                atomicOr(&flags[root >> 5], 1u << (root & 31));
            }
            for (int c = t; c < C2; c += 1024) cb[c] = ~0ull;
            __syncthreads();
            if (t == 0) {
                int sacc = 0;
                for (int w = 0; w < CMAX2 / 32; ++w) sacc += __popc(flags[w]);
                ncs = sacc;
            }
            __syncthreads();
            nc = ncs;
        }
        if (t == 0) numComp[m] = nc;
    }
    __syncthreads();

    // ---- fused bitonic sort of deaths[m][0..N-2] (+ BIG pad).
    // Same-block global writes above are visible after __syncthreads.
    for (int i = t; i < N; i += 1024)
        s[i] = (i < N - 1) ? dth[i] : BIG;
    __syncthreads();
    for (int k = 2; k <= N; k <<= 1) {
        for (int jj = k >> 1; jj > 0; jj >>= 1) {
            for (int i = t; i < N; i += 1024) {
                int ixj = i ^ jj;
                if (ixj > i) {
                    float a = s[i], b = s[ixj];
                    bool up = ((i & k) == 0);
                    bool sw = up ? (a > b) : (a < b);
                    if (sw) { s[i] = b; s[ixj] = a; }
                }
            }
            __syncthreads();
        }
    }
    for (int i = t; i < N; i += 1024) dth[i] = s[i];
}

// ---------------- final: W1 + L2 (sums accumArr partials)
__global__ __launch_bounds__(1024) void final_kernel(const float* __restrict__ s1,
                                                     const float* __restrict__ s2,
                                                     const float* __restrict__ accumArr,
                                                     float* __restrict__ out) {
    __shared__ float wsum[16];
    __shared__ float rsum[16];
    float sum = 0.f;
    for (int i = threadIdx.x; i < N - 1; i += 1024) {
        float a = s1[i], b = s2[i];
        sum += fminf(fabsf(a - b), 0.5f * (a + b));
    }
    float ra = accumArr[threadIdx.x];
#pragma unroll
    for (int off = 32; off > 0; off >>= 1) {
        sum += __shfl_down(sum, off, 64);
        ra += __shfl_down(ra, off, 64);
    }
    int lane = threadIdx.x & 63, wid = threadIdx.x >> 6;
    if (lane == 0) { wsum[wid] = sum; rsum[wid] = ra; }
    __syncthreads();
    if (threadIdx.x == 0) {
        float tot = 0.f, rt = 0.f;
        for (int k = 0; k < 16; ++k) { tot += wsum[k]; rt += rsum[k]; }
        out[0] = rt * (1.0f / ((float)N * (float)D)) + tot;
    }
}

extern "C" void kernel_launch(void* const* d_in, const int* in_sizes, int n_in,
                              void* d_out, int out_size, void* d_ws, size_t ws_size,
                              hipStream_t stream) {
    const float* x1 = (const float*)d_in[0];
    const float* x2 = (const float*)d_in[1];
    float* out = (float*)d_out;
    float* ws = (float*)d_ws;

    const size_t nn = (size_t)N * N;
    const size_t cc2 = (size_t)CMAX * CMAX;

    float* dist1 = ws;
    float* dist2 = ws + nn;
    float* distc = ws + 2 * nn;
    u16* h1 = (u16*)distc;                 // alias: dead before colmin_b writes distc
    u16* h2 = h1 + (size_t)N * D;
    u64* compBest = (u64*)(distc + 2 * cc2);
    int* comp      = (int*)(compBest + 2 * N);
    int* comp_c    = comp + 2 * N;
    int* memberList = comp_c + 2 * CMAX;
    int* compStart  = memberList + 2 * N;
    float* deaths  = (float*)(compStart + 2 * (CMAX + 1));
    int* cnt       = (int*)(deaths + 2 * N);
    int* numComp   = cnt + 2;
    int* numC1     = numComp + 2;
    float* accum   = (float*)(numC1 + 2);
    float* sq      = accum + 2;
    int* taskOff   = (int*)(sq + 2 * N);
    int* task_c    = taskOff + 2 * (CMAX + 1);
    int* task_s0   = task_c + 2 * TMAX;
    int* task_s1   = task_s0 + 2 * TMAX;
    float* accumArr = (float*)(task_s1 + 2 * TMAX);   // 1024 floats
    // level-2 buffers alias dist1 (dead after colmin) — initialized in merge2_kernel,
    // NEVER earlier (R7 crash: init before gemm overwrote them -> OOB)
    float* distc2  = dist1;
    int* comp_c2   = (int*)(distc2 + 2 * (size_t)CMAX2 * CMAX2);
    int* memberList2 = comp_c2 + 2 * CMAX2;
    int* compStart2  = memberList2 + 2 * CMAX;
    int* numC2       = compStart2 + 2 * (CMAX2 + 1);

    prep_kernel<<<N / 4, 256, 0, stream>>>(x1, x2, h1, h2, sq, accumArr, comp, compBest, comp_c);
    gemm_dist_kernel<<<dim3(N / BN, N / BM, 2), 256, 0, stream>>>(h1, h2, sq, dist1, dist2, compBest);
    merge1_kernel<<<2, 1024, 0, stream>>>(comp, compBest, deaths, cnt, numComp, numC1,
                                          memberList, compStart, taskOff, task_c, task_s0, task_s1);
    rowmin_kernel<<<dim3(N, 2), 256, 0, stream>>>(dist1, dist2, comp);
    colmin_a_kernel<<<dim3(TMAX, CMAX / 256, 2), 256, 0, stream>>>(dist1, dist2, memberList,
                                                                   taskOff, task_c, task_s0, task_s1);
    colmin_b_kernel<<<dim3(CMAX, CMAX / 256, 2), 256, 0, stream>>>(dist1, dist2, taskOff, numC1,
                                                                   distc, compBest);
    merge2_kernel<<<2, 1024, 0, stream>>>(comp_c, compBest, deaths, cnt, numComp, numC1, numC2,
                                          memberList2, compStart2, comp_c2);
    rowmin2_kernel<<<dim3(CMAX, 2), 256, 0, stream>>>(distc, comp_c, numC1);
    colmin2_kernel<<<dim3(CMAX2, CMAX2 / 256, 2), 256, 0, stream>>>(distc, memberList2, compStart2, numC2, distc2);
    finish_kernel<<<2, 1024, 0, stream>>>(distc2, comp_c2, deaths, cnt, numComp, numC2);
    final_kernel<<<1, 1024, 0, stream>>>(deaths, deaths + N, accumArr, out);
}

// Round 16
// 286.858 us; speedup vs baseline: 1.1454x; 1.0991x over previous
//
#include <hip/hip_runtime.h>

#define N 4096
#define D 512
#define BIG 1e30f
#define CMAX 2048
#define CMAX2 1024
#define NW (N / 32)

typedef unsigned long long u64;
typedef unsigned short u16;
typedef _Float16 f16x8 __attribute__((ext_vector_type(8)));
typedef float floatx4 __attribute__((ext_vector_type(4)));

// ---------------- fused prep: f32->f16 convert + row sq-norms + repr partial + init
__global__ __launch_bounds__(256) void prep_kernel(const float* __restrict__ x1,
                                                   const float* __restrict__ x2,
                                                   u16* __restrict__ h1,
                                                   u16* __restrict__ h2,
                                                   float* __restrict__ sq,
                                                   float* __restrict__ accumArr,
                                                   int* __restrict__ comp,
                                                   u64* __restrict__ compBest,
                                                   int* __restrict__ comp_c) {
    const int tid = blockIdx.x * 256 + threadIdx.x;
    if (tid < 2 * N) {
        comp[tid] = tid & (N - 1);
        compBest[tid] = ~0ull;
    }
    if (tid < 2 * CMAX) comp_c[tid] = tid & (CMAX - 1);

    const int wave = threadIdx.x >> 6, lane = threadIdx.x & 63;
    const int row = blockIdx.x * 4 + wave;
    const float4* r1 = (const float4*)(x1 + (size_t)row * D);
    const float4* r2 = (const float4*)(x2 + (size_t)row * D);
    float4 a0 = r1[lane * 2], a1 = r1[lane * 2 + 1];
    float4 b0 = r2[lane * 2], b1 = r2[lane * 2 + 1];
    ushort4* o1 = (ushort4*)(h1 + (size_t)row * D + lane * 8);
    ushort4* o2 = (ushort4*)(h2 + (size_t)row * D + lane * 8);
    o1[0] = make_ushort4(__builtin_bit_cast(u16, (_Float16)a0.x), __builtin_bit_cast(u16, (_Float16)a0.y),
                         __builtin_bit_cast(u16, (_Float16)a0.z), __builtin_bit_cast(u16, (_Float16)a0.w));
    o1[1] = make_ushort4(__builtin_bit_cast(u16, (_Float16)a1.x), __builtin_bit_cast(u16, (_Float16)a1.y),
                         __builtin_bit_cast(u16, (_Float16)a1.z), __builtin_bit_cast(u16, (_Float16)a1.w));
    o2[0] = make_ushort4(__builtin_bit_cast(u16, (_Float16)b0.x), __builtin_bit_cast(u16, (_Float16)b0.y),
                         __builtin_bit_cast(u16, (_Float16)b0.z), __builtin_bit_cast(u16, (_Float16)b0.w));
    o2[1] = make_ushort4(__builtin_bit_cast(u16, (_Float16)b1.x), __builtin_bit_cast(u16, (_Float16)b1.y),
                         __builtin_bit_cast(u16, (_Float16)b1.z), __builtin_bit_cast(u16, (_Float16)b1.w));
    float s1 = 0.f, s2 = 0.f, sr = 0.f;
    float av[8] = {a0.x, a0.y, a0.z, a0.w, a1.x, a1.y, a1.z, a1.w};
    float bv[8] = {b0.x, b0.y, b0.z, b0.w, b1.x, b1.y, b1.z, b1.w};
#pragma unroll
    for (int e = 0; e < 8; ++e) {
        s1 = fmaf(av[e], av[e], s1);
        s2 = fmaf(bv[e], bv[e], s2);
        float d = av[e] - bv[e];
        sr = fmaf(d, d, sr);
    }
#pragma unroll
    for (int off = 32; off > 0; off >>= 1) {
        s1 += __shfl_down(s1, off, 64);
        s2 += __shfl_down(s2, off, 64);
        sr += __shfl_down(sr, off, 64);
    }
    __shared__ float wsr[4];
    if (lane == 0) {
        sq[row] = s1;
        sq[N + row] = s2;
        wsr[wave] = sr;
    }
    __syncthreads();
    if (threadIdx.x == 0)
        accumArr[blockIdx.x] = wsr[0] + wsr[1] + wsr[2] + wsr[3];
}

// ---------------- single-pass f16 MFMA GEMM + dist epilogue + fused round-1 row argmin
// R15 config (measured best 82-105 band) — unchanged.
#define BM 128
#define BN 128
#define BK 32

__global__ __launch_bounds__(256) void gemm_dist_kernel(const u16* __restrict__ h1,
                                                        const u16* __restrict__ h2,
                                                        const float* __restrict__ sqn,
                                                        float* __restrict__ dist1,
                                                        float* __restrict__ dist2,
                                                        u64* __restrict__ compBest) {
    const int m = blockIdx.z;
    const u16* H = m ? h2 : h1;
    const float* SQ = sqn + (size_t)m * N;
    float* dist = m ? dist2 : dist1;
    u64* cb = compBest + (size_t)m * N;

    __shared__ u16 SH[2 * BM * BK];
    u16* Ah = SH;
    u16* Bh = SH + BM * BK;

    const int tid = threadIdx.x;
    const int wave = tid >> 6, lane = tid & 63;
    const int wm = wave >> 1, wn = wave & 1;
    const int row0 = blockIdx.y * BM, col0 = blockIdx.x * BN;

    floatx4 acc[4][4] = {};

    const int srow = lane >> 2;
    const int scol = (lane & 3) * 8;

    for (int k0 = 0; k0 < D; k0 += BK) {
        __syncthreads();
#pragma unroll
        for (int i = 0; i < 2; ++i) {
            const int rb = wave * 32 + i * 16;
            const u16* ga = H + (size_t)(row0 + rb + srow) * D + k0 + scol;
            const u16* gb = H + (size_t)(col0 + rb + srow) * D + k0 + scol;
            __builtin_amdgcn_global_load_lds(
                (const __attribute__((address_space(1))) unsigned int*)ga,
                (__attribute__((address_space(3))) unsigned int*)&Ah[rb * BK], 16, 0, 0);
            __builtin_amdgcn_global_load_lds(
                (const __attribute__((address_space(1))) unsigned int*)gb,
                (__attribute__((address_space(3))) unsigned int*)&Bh[rb * BK], 16, 0, 0);
        }
        __syncthreads();

        const int fo = (lane >> 4) * 8;
        const int fm = lane & 15;
        f16x8 a8[4], b8[4];
#pragma unroll
        for (int s = 0; s < 4; ++s) {
            a8[s] = *(const f16x8*)&Ah[(wm * 64 + s * 16 + fm) * BK + fo];
            b8[s] = *(const f16x8*)&Bh[(wn * 64 + s * 16 + fm) * BK + fo];
        }
#pragma unroll
        for (int i = 0; i < 4; ++i)
#pragma unroll
            for (int j = 0; j < 4; ++j)
                acc[i][j] = __builtin_amdgcn_mfma_f32_16x16x32_f16(a8[i], b8[j], acc[i][j], 0, 0, 0);
    }

    __syncthreads();
    float* Cs = (float*)SH + wave * 1024;

    const int lr = lane & 15;
    const int lq = lane >> 4;
    float sc[4];
#pragma unroll
    for (int ns = 0; ns < 4; ++ns) sc[ns] = SQ[col0 + wn * 64 + ns * 16 + lr];
#pragma unroll
    for (int ms = 0; ms < 4; ++ms) {
        const int rb = row0 + wm * 64 + ms * 16 + lq * 4;
        float srow_[4];
#pragma unroll
        for (int r = 0; r < 4; ++r) srow_[r] = SQ[rb + r];
#pragma unroll
        for (int r = 0; r < 4; ++r) {
            const int row = rb + r;
            float dval[4];
#pragma unroll
            for (int ns = 0; ns < 4; ++ns) {
                const int col = col0 + wn * 64 + ns * 16 + lr;
                float d2 = srow_[r] + sc[ns] - 2.0f * acc[ms][ns][r];
                dval[ns] = (row == col) ? BIG : sqrtf(fmaxf(d2, 1e-12f));
            }
            float vmin = fminf(fminf(dval[0], dval[1]), fminf(dval[2], dval[3]));
            int nsel = (dval[0] == vmin) ? 0 : (dval[1] == vmin) ? 1 : (dval[2] == vmin) ? 2 : 3;
            u64 pmin = (((u64)__float_as_uint(vmin)) << 32) | (unsigned)(col0 + wn * 64 + nsel * 16 + lr);
#pragma unroll
            for (int msk = 1; msk < 16; msk <<= 1) {
                u64 o = __shfl_xor(pmin, msk, 64);
                pmin = o < pmin ? o : pmin;
            }
            if (lr == 0) atomicMin(&cb[row], pmin);
#pragma unroll
            for (int ns = 0; ns < 4; ++ns)
                Cs[(lq * 4 + r) * 64 + ns * 16 + lr] = dval[ns];
        }
#pragma unroll
        for (int p = 0; p < 4; ++p) {
            float4 v4 = *(float4*)&Cs[p * 256 + lane * 4];
            const int gr = row0 + wm * 64 + ms * 16 + p * 4 + (lane >> 4);
            const int gc = col0 + wn * 64 + (lane & 15) * 4;
            *(float4*)&dist[(size_t)gr * N + gc] = v4;
        }
    }
}

// ---------------- distc init to +inf (must run after gemm: h1/h2 alias this region)
__global__ __launch_bounds__(256) void distc_init_kernel(unsigned* __restrict__ distc_u) {
    const size_t i = (size_t)blockIdx.x * 256 + threadIdx.x;
    uint4 v = make_uint4(0x7f800000u, 0x7f800000u, 0x7f800000u, 0x7f800000u);
    ((uint4*)distc_u)[i] = v;
}

// ---------------- merge round 1 (trimmed: no member lists / task build needed anymore)
__global__ __launch_bounds__(1024) void merge1_kernel(int* __restrict__ comp,
                                                      u64* __restrict__ compBest,
                                                      float* __restrict__ deaths,
                                                      int* __restrict__ cnt,
                                                      int* __restrict__ numComp,
                                                      int* __restrict__ numC1) {
    const int m = blockIdx.x;
    int* cp = comp + (size_t)m * N;
    u64* cb = compBest + (size_t)m * N;
    float* dth = deaths + (size_t)m * N;
    const int t = threadIdx.x;

    __shared__ int pa[N];
    __shared__ int pb[N];
    __shared__ unsigned flagbits[NW];
    __shared__ int wpc[NW];
    __shared__ int done;

    if (t == 0) cnt[m] = 0;
    __syncthreads();

    for (int c = t; c < N; c += 1024) {
        u64 best = cb[c];
        int p = c;
        if (best != ~0ull) {
            int j = (int)(unsigned)best;
            int c2 = cp[j];
            u64 best2 = cb[c2];
            int j2 = (int)(unsigned)best2;
            bool mutual = (cp[j2] == c);
            if (!(mutual && c < c2)) {
                p = c2;
                int idx = atomicAdd(cnt + m, 1);
                dth[idx] = __uint_as_float((unsigned)(best >> 32));
            }
        }
        pa[c] = p;
    }

    int* A = pa;
    int* B = pb;
    while (true) {
        __syncthreads();
        if (t == 0) done = 1;
        __syncthreads();
        bool ch = false;
        for (int c = t; c < N; c += 1024) {
            int g = A[A[c]];
            B[c] = g;
            ch |= (g != A[c]);
        }
        if (ch) done = 0;
        __syncthreads();
        int* tmp = A; A = B; B = tmp;
        if (done) break;
    }

    for (int w = t; w < NW; w += 1024) flagbits[w] = 0u;
    __syncthreads();
    for (int i = t; i < N; i += 1024)
        atomicOr(&flagbits[A[i] >> 5], 1u << (A[i] & 31));
    __syncthreads();
    if (t < NW) wpc[t] = __popc(flagbits[t]);
    __syncthreads();
    for (int off = 1; off < NW; off <<= 1) {
        int v = 0;
        if (t < NW) v = wpc[t] + ((t >= off) ? wpc[t - off] : 0);
        __syncthreads();
        if (t < NW) wpc[t] = v;
        __syncthreads();
    }
    for (int i = t; i < N; i += 1024) {
        int root = A[i];
        int w = root >> 5, b = root & 31;
        int base = w ? wpc[w - 1] : 0;
        unsigned mask = b ? ((1u << b) - 1u) : 0u;
        cp[i] = base + __popc(flagbits[w] & mask);
    }
    for (int c = t; c < N; c += 1024) cb[c] = ~0ull;
    if (t == 0) {
        int C1 = wpc[NW - 1];
        numC1[m] = C1;
        numComp[m] = C1;
    }
}

// ---------------- atomic contraction: per-row LDS bins + global atomicMin into distc row
// (replaces rowmin + colmin_a + colmin_b; distc L2-resident so RMWs are cheap; same-comp
// contamination only reaches cells excluded by scan_c/rowmin2/colmin2/finish)
__global__ __launch_bounds__(256) void rowatomic_kernel(const float* __restrict__ dist1,
                                                        const float* __restrict__ dist2,
                                                        const int* __restrict__ comp,
                                                        unsigned* __restrict__ distc_u) {
    const int m = blockIdx.y;
    const float* dist = m ? dist2 : dist1;
    const int* cp = comp + (size_t)m * N;
    const int i = blockIdx.x;
    const float4* row4 = (const float4*)(dist + (size_t)i * N);
    const int4* cp4 = (const int4*)cp;
    __shared__ unsigned bins[CMAX];
    const int t = threadIdx.x;
    for (int b = t; b < CMAX; b += 256) bins[b] = 0x7f800000u;
    __syncthreads();
#pragma unroll
    for (int k = 0; k < 4; ++k) {
        int q = t + 256 * k;
        float4 v = row4[q];
        int4 cj = cp4[q];
        atomicMin(&bins[cj.x], __float_as_uint(v.x));
        atomicMin(&bins[cj.y], __float_as_uint(v.y));
        atomicMin(&bins[cj.z], __float_as_uint(v.z));
        atomicMin(&bins[cj.w], __float_as_uint(v.w));
    }
    __syncthreads();
    unsigned* drow = distc_u + ((size_t)m * CMAX + cp[i]) * CMAX;
    for (int b = t; b < CMAX; b += 256) {
        unsigned v = bins[b];
        if (v != 0x7f800000u) atomicMin(&drow[b], v);
    }
}

// ---------------- round-2 scan on distc (comp_c identity)
__global__ __launch_bounds__(256) void scan_c_kernel(const float* __restrict__ distc,
                                                     const int* __restrict__ comp_c,
                                                     u64* __restrict__ compBest,
                                                     const int* __restrict__ numComp,
                                                     const int* __restrict__ numC1) {
    const int m = blockIdx.y;
    if (numComp[m] <= 1) return;
    const int C1 = numC1[m];
    const int r = blockIdx.x;
    if (r >= C1) return;
    const int* cc = comp_c + (size_t)m * CMAX;
    u64* cb = compBest + (size_t)m * N;
    const int myc = cc[r];
    const float4* row4 = (const float4*)(distc + ((size_t)m * CMAX + r) * CMAX);
    const int4* cc4 = (const int4*)cc;
    const int t = threadIdx.x;
    u64 best = ~0ull;
#pragma unroll
    for (int k = 0; k < 2; ++k) {
        int q = t + 256 * k;
        float4 v = row4[q];
        int4 cj = cc4[q];
        int j0 = q * 4;
        u64 p0 = (j0 + 0 < C1 && cj.x != myc) ? ((((u64)__float_as_uint(v.x)) << 32) | (unsigned)(j0 + 0)) : ~0ull;
        u64 p1 = (j0 + 1 < C1 && cj.y != myc) ? ((((u64)__float_as_uint(v.y)) << 32) | (unsigned)(j0 + 1)) : ~0ull;
        u64 p2 = (j0 + 2 < C1 && cj.z != myc) ? ((((u64)__float_as_uint(v.z)) << 32) | (unsigned)(j0 + 2)) : ~0ull;
        u64 p3 = (j0 + 3 < C1 && cj.w != myc) ? ((((u64)__float_as_uint(v.w)) << 32) | (unsigned)(j0 + 3)) : ~0ull;
        u64 q0 = p0 < p1 ? p0 : p1;
        u64 q1 = p2 < p3 ? p2 : p3;
        u64 qq = q0 < q1 ? q0 : q1;
        best = qq < best ? qq : best;
    }
#pragma unroll
    for (int off = 32; off > 0; off >>= 1) {
        u64 o = __shfl_down(best, off, 64);
        best = o < best ? o : best;
    }
    if ((t & 63) == 0) atomicMin(cb + myc, best);
}

// ---------------- merge round 2 + dense relabel to level-2 + member lists
__global__ __launch_bounds__(1024) void merge2_kernel(int* __restrict__ comp_c,
                                                      u64* __restrict__ compBest,
                                                      float* __restrict__ deaths,
                                                      int* __restrict__ cnt,
                                                      int* __restrict__ numComp,
                                                      const int* __restrict__ numC1,
                                                      int* __restrict__ numC2,
                                                      int* __restrict__ memberList2,
                                                      int* __restrict__ compStart2,
                                                      int* __restrict__ comp_c2) {
    const int m = blockIdx.x;
    const int t = threadIdx.x;
    const int C1 = numC1[m];
    int* cc2i = comp_c2 + (size_t)m * CMAX2;
    for (int c = t; c < CMAX2; c += 1024) cc2i[c] = c;
    int* cs = compStart2 + (size_t)m * (CMAX2 + 1);
    if (numComp[m] <= 1) {
        for (int c = t; c <= CMAX2; c += 1024) cs[c] = 0;
        if (t == 0) numC2[m] = numComp[m];
        return;
    }
    int* cc = comp_c + (size_t)m * CMAX;
    u64* cb = compBest + (size_t)m * N;
    float* dth = deaths + (size_t)m * N;
    int* ml = memberList2 + (size_t)m * CMAX;

    __shared__ int pa[CMAX];
    __shared__ int pb[CMAX];
    __shared__ unsigned flagbits[CMAX / 32];
    __shared__ int wpc[CMAX / 32];
    __shared__ int cnts[CMAX2];
    __shared__ int cnts2s[CMAX2];
    __shared__ int done;

    for (int c = t; c < C1; c += 1024) {
        u64 best = cb[c];
        int p = c;
        if (best != ~0ull) {
            int j = (int)(unsigned)best;
            int c2 = cc[j];
            u64 best2 = cb[c2];
            int j2 = (int)(unsigned)best2;
            bool mutual = (cc[j2] == c);
            if (!(mutual && c < c2)) {
                p = c2;
                int idx = atomicAdd(cnt + m, 1);
                dth[idx] = __uint_as_float((unsigned)(best >> 32));
            }
        }
        pa[c] = p;
    }

    int* A = pa;
    int* B = pb;
    while (true) {
        __syncthreads();
        if (t == 0) done = 1;
        __syncthreads();
        bool ch = false;
        for (int c = t; c < C1; c += 1024) {
            int g = A[A[c]];
            B[c] = g;
            ch |= (g != A[c]);
        }
        if (ch) done = 0;
        __syncthreads();
        int* tmp = A; A = B; B = tmp;
        if (done) break;
    }

    for (int w = t; w < CMAX / 32; w += 1024) flagbits[w] = 0u;
    __syncthreads();
    for (int j = t; j < C1; j += 1024)
        atomicOr(&flagbits[A[j] >> 5], 1u << (A[j] & 31));
    __syncthreads();
    if (t < CMAX / 32) wpc[t] = __popc(flagbits[t]);
    __syncthreads();
    for (int off = 1; off < CMAX / 32; off <<= 1) {
        int v = 0;
        if (t < CMAX / 32) v = wpc[t] + ((t >= off) ? wpc[t - off] : 0);
        __syncthreads();
        if (t < CMAX / 32) wpc[t] = v;
        __syncthreads();
    }
    for (int j = t; j < C1; j += 1024) {
        int root = A[j];
        int w = root >> 5, b = root & 31;
        int base = w ? wpc[w - 1] : 0;
        unsigned mask = b ? ((1u << b) - 1u) : 0u;
        cc[j] = base + __popc(flagbits[w] & mask);
    }
    for (int c = t; c < CMAX2; c += 1024) cnts[c] = 0;
    __syncthreads();
    for (int j = t; j < C1; j += 1024) atomicAdd(&cnts[cc[j]], 1);
    __syncthreads();
    int* S = cnts; int* T_ = cnts2s;
    for (int off = 1; off < CMAX2; off <<= 1) {
        for (int c = t; c < CMAX2; c += 1024)
            T_[c] = S[c] + ((c >= off) ? S[c - off] : 0);
        __syncthreads();
        int* tmp = S; S = T_; T_ = tmp;
    }
    for (int c = t; c <= CMAX2; c += 1024) cs[c] = (c == 0) ? 0 : S[c - 1];
    for (int c = t; c < CMAX2; c += 1024) T_[c] = (c == 0) ? 0 : S[c - 1];
    __syncthreads();
    for (int j = t; j < C1; j += 1024) {
        int pos = atomicAdd(&T_[cc[j]], 1);
        ml[pos] = j;
    }
    for (int c = t; c < C1; c += 1024) cb[c] = ~0ull;
    if (t == 0) {
        int C2 = wpc[CMAX / 32 - 1];
        numC2[m] = C2;
        numComp[m] = C2;
    }
}

// ---------------- level-2 contraction phase A
__global__ __launch_bounds__(256) void rowmin2_kernel(float* __restrict__ distc,
                                                      const int* __restrict__ comp_c,
                                                      const int* __restrict__ numC1) {
    const int m = blockIdx.y;
    const int C1 = numC1[m];
    const int r = blockIdx.x;
    if (r >= C1) return;
    const int* cc = comp_c + (size_t)m * CMAX;
    float* row = distc + ((size_t)m * CMAX + r) * CMAX;
    __shared__ unsigned bins[CMAX2];
    const int t = threadIdx.x;
    for (int b = t; b < CMAX2; b += 256) bins[b] = 0x7f800000u;
    __syncthreads();
    for (int j = t; j < C1; j += 256) {
        float v = row[j];
        atomicMin(&bins[cc[j]], __float_as_uint(v));
    }
    __syncthreads();
    for (int b = t; b < CMAX2; b += 256) row[b] = __uint_as_float(bins[b]);
}

// ---------------- level-2 contraction phase B -> distc2
__global__ __launch_bounds__(256) void colmin2_kernel(const float* __restrict__ distc,
                                                      const int* __restrict__ memberList2,
                                                      const int* __restrict__ compStart2,
                                                      const int* __restrict__ numC2,
                                                      float* __restrict__ distc2) {
    const int m = blockIdx.z;
    const int c = blockIdx.x;
    const int C2 = numC2[m];
    if (c >= C2) return;
    const int* ml = memberList2 + (size_t)m * CMAX;
    const int* cs = compStart2 + (size_t)m * (CMAX2 + 1);
    const int b = blockIdx.y * 256 + threadIdx.x;
    const int s0 = cs[c], s1 = cs[c + 1];
    float mn = BIG;
    for (int k = s0; k < s1; ++k) {
        const int r = ml[k];
        float v = distc[((size_t)m * CMAX + r) * CMAX + b];
        mn = fminf(mn, v);
    }
    distc2[((size_t)m * CMAX2 + c) * CMAX2 + b] = (b == c) ? BIG : mn;
}

// ---------------- finish: ALL rounds >= 3 + FUSED bitonic sort of this matrix's deaths
__global__ __launch_bounds__(1024) void finish_kernel(const float* __restrict__ distc2,
                                                      const int* __restrict__ comp_c2,
                                                      float* __restrict__ deaths,
                                                      int* __restrict__ cnt,
                                                      int* __restrict__ numComp,
                                                      const int* __restrict__ numC2) {
    const int m = blockIdx.x;
    int nc = numComp[m];
    const int C2 = numC2[m];
    const float* Dm = distc2 + (size_t)m * CMAX2 * CMAX2;
    float* dth = deaths + (size_t)m * N;
    const int t = threadIdx.x;
    const int wave = t >> 6, lane = t & 63;
    __shared__ int comp[CMAX2];
    __shared__ u64 cb[CMAX2];
    __shared__ int pa[CMAX2];
    __shared__ int pb[CMAX2];
    __shared__ unsigned flags[CMAX2 / 32];
    __shared__ int done, ncs;
    __shared__ float s[N];

    if (nc > 1) {
        for (int c = t; c < C2; c += 1024) {
            comp[c] = comp_c2[(size_t)m * CMAX2 + c];
            cb[c] = ~0ull;
        }
        __syncthreads();

        for (int round = 0; round < 10 && nc > 1; ++round) {
            for (int r = wave; r < C2; r += 16) {
                const int myc = comp[r];
                const float* row = Dm + (size_t)r * CMAX2;
                u64 best = ~0ull;
                for (int j = lane; j < C2; j += 64) {
                    if (comp[j] != myc) {
                        u64 p = (((u64)__float_as_uint(row[j])) << 32) | (unsigned)j;
                        best = p < best ? p : best;
                    }
                }
#pragma unroll
                for (int off = 32; off > 0; off >>= 1) {
                    u64 o = __shfl_down(best, off, 64);
                    best = o < best ? o : best;
                }
                if (lane == 0) atomicMin(&cb[myc], best);
            }
            __syncthreads();
            for (int c = t; c < C2; c += 1024) {
                u64 best = cb[c];
                int p = c;
                if (best != ~0ull) {
                    int j = (int)(unsigned)best;
                    int c2 = comp[j];
                    u64 best2 = cb[c2];
                    int j2 = (int)(unsigned)best2;
                    bool mutual = (comp[j2] == c);
                    if (!(mutual && c < c2)) {
                        p = c2;
                        int idx = atomicAdd(cnt + m, 1);
                        dth[idx] = __uint_as_float((unsigned)(best >> 32));
                    }
                }
                pa[c] = p;
            }
            int* A = pa; int* B = pb;
            while (true) {
                __syncthreads();
                if (t == 0) done = 1;
                __syncthreads();
                bool ch = false;
                for (int c = t; c < C2; c += 1024) {
                    int g = A[A[c]];
                    B[c] = g;
                    ch |= (g != A[c]);
                }
                if (ch) done = 0;
                __syncthreads();
                int* tmp = A; A = B; B = tmp;
                if (done) break;
            }
            for (int w = t; w < CMAX2 / 32; w += 1024) flags[w] = 0u;
            __syncthreads();
            for (int j = t; j < C2; j += 1024) {
                int root = A[comp[j]];
                comp[j] = root;
                atomicOr(&flags[root >> 5], 1u << (root & 31));
            }
            for (int c = t; c < C2; c += 1024) cb[c] = ~0ull;
            __syncthreads();
            if (t == 0) {
                int sacc = 0;
                for (int w = 0; w < CMAX2 / 32; ++w) sacc += __popc(flags[w]);
                ncs = sacc;
            }
            __syncthreads();
            nc = ncs;
        }
        if (t == 0) numComp[m] = nc;
    }
    __syncthreads();

    for (int i = t; i < N; i += 1024)
        s[i] = (i < N - 1) ? dth[i] : BIG;
    __syncthreads();
    for (int k = 2; k <= N; k <<= 1) {
        for (int jj = k >> 1; jj > 0; jj >>= 1) {
            for (int i = t; i < N; i += 1024) {
                int ixj = i ^ jj;
                if (ixj > i) {
                    float a = s[i], b = s[ixj];
                    bool up = ((i & k) == 0);
                    bool sw = up ? (a > b) : (a < b);
                    if (sw) { s[i] = b; s[ixj] = a; }
                }
            }
            __syncthreads();
        }
    }
    for (int i = t; i < N; i += 1024) dth[i] = s[i];
}

// ---------------- final: W1 + L2 (sums accumArr partials)
__global__ __launch_bounds__(1024) void final_kernel(const float* __restrict__ s1,
                                                     const float* __restrict__ s2,
                                                     const float* __restrict__ accumArr,
                                                     float* __restrict__ out) {
    __shared__ float wsum[16];
    __shared__ float rsum[16];
    float sum = 0.f;
    for (int i = threadIdx.x; i < N - 1; i += 1024) {
        float a = s1[i], b = s2[i];
        sum += fminf(fabsf(a - b), 0.5f * (a + b));
    }
    float ra = accumArr[threadIdx.x];
#pragma unroll
    for (int off = 32; off > 0; off >>= 1) {
        sum += __shfl_down(sum, off, 64);
        ra += __shfl_down(ra, off, 64);
    }
    int lane = threadIdx.x & 63, wid = threadIdx.x >> 6;
    if (lane == 0) { wsum[wid] = sum; rsum[wid] = ra; }
    __syncthreads();
    if (threadIdx.x == 0) {
        float tot = 0.f, rt = 0.f;
        for (int k = 0; k < 16; ++k) { tot += wsum[k]; rt += rsum[k]; }
        out[0] = rt * (1.0f / ((float)N * (float)D)) + tot;
    }
}

extern "C" void kernel_launch(void* const* d_in, const int* in_sizes, int n_in,
                              void* d_out, int out_size, void* d_ws, size_t ws_size,
                              hipStream_t stream) {
    const float* x1 = (const float*)d_in[0];
    const float* x2 = (const float*)d_in[1];
    float* out = (float*)d_out;
    float* ws = (float*)d_ws;

    const size_t nn = (size_t)N * N;
    const size_t cc2 = (size_t)CMAX * CMAX;

    float* dist1 = ws;
    float* dist2 = ws + nn;
    float* distc = ws + 2 * nn;
    u16* h1 = (u16*)distc;                 // alias: dead before distc_init overwrites
    u16* h2 = h1 + (size_t)N * D;
    u64* compBest = (u64*)(distc + 2 * cc2);
    int* comp      = (int*)(compBest + 2 * N);
    int* comp_c    = comp + 2 * N;
    float* deaths  = (float*)(comp_c + 2 * CMAX);
    int* cnt       = (int*)(deaths + 2 * N);
    int* numComp   = cnt + 2;
    int* numC1     = numComp + 2;
    float* sq      = (float*)(numC1 + 2);
    float* accumArr = sq + 2 * N;          // 1024 floats
    // level-2 buffers alias dist1 (dead after rowatomic) — initialized in merge2_kernel,
    // NEVER earlier (R7 crash: init before gemm overwrote them -> OOB)
    float* distc2  = dist1;
    int* comp_c2   = (int*)(distc2 + 2 * (size_t)CMAX2 * CMAX2);
    int* memberList2 = comp_c2 + 2 * CMAX2;
    int* compStart2  = memberList2 + 2 * CMAX;
    int* numC2       = compStart2 + 2 * (CMAX2 + 1);

    prep_kernel<<<N / 4, 256, 0, stream>>>(x1, x2, h1, h2, sq, accumArr, comp, compBest, comp_c);
    gemm_dist_kernel<<<dim3(N / BN, N / BM, 2), 256, 0, stream>>>(h1, h2, sq, dist1, dist2, compBest);
    distc_init_kernel<<<(2 * cc2 / 4) / 256, 256, 0, stream>>>((unsigned*)distc);
    merge1_kernel<<<2, 1024, 0, stream>>>(comp, compBest, deaths, cnt, numComp, numC1);
    rowatomic_kernel<<<dim3(N, 2), 256, 0, stream>>>(dist1, dist2, comp, (unsigned*)distc);
    scan_c_kernel<<<dim3(CMAX, 2), 256, 0, stream>>>(distc, comp_c, compBest, numComp, numC1);
    merge2_kernel<<<2, 1024, 0, stream>>>(comp_c, compBest, deaths, cnt, numComp, numC1, numC2,
                                          memberList2, compStart2, comp_c2);
    rowmin2_kernel<<<dim3(CMAX, 2), 256, 0, stream>>>(distc, comp_c, numC1);
    colmin2_kernel<<<dim3(CMAX2, CMAX2 / 256, 2), 256, 0, stream>>>(distc, memberList2, compStart2, numC2, distc2);
    finish_kernel<<<2, 1024, 0, stream>>>(distc2, comp_c2, deaths, cnt, numComp, numC2);
    final_kernel<<<1, 1024, 0, stream>>>(deaths, deaths + N, accumArr, out);
}

// Round 17
// 267.116 us; speedup vs baseline: 1.2301x; 1.0739x over previous
//
#include <hip/hip_runtime.h>

#define N 4096
#define D 512
#define BIG 1e30f
#define CMAX 2048
#define CMAX2 1024
#define NW (N / 32)

typedef unsigned long long u64;
typedef unsigned short u16;
typedef _Float16 f16x8 __attribute__((ext_vector_type(8)));
typedef float floatx4 __attribute__((ext_vector_type(4)));

// ---------------- fused prep: f32->f16 convert + row sq-norms + repr partial + init
__global__ __launch_bounds__(256) void prep_kernel(const float* __restrict__ x1,
                                                   const float* __restrict__ x2,
                                                   u16* __restrict__ h1,
                                                   u16* __restrict__ h2,
                                                   float* __restrict__ sq,
                                                   float* __restrict__ accumArr,
                                                   int* __restrict__ comp,
                                                   u64* __restrict__ compBest,
                                                   int* __restrict__ comp_c,
                                                   int* __restrict__ doneFlag) {
    const int tid = blockIdx.x * 256 + threadIdx.x;
    if (tid < 2 * N) {
        comp[tid] = tid & (N - 1);
        compBest[tid] = ~0ull;
    }
    if (tid < 2 * CMAX) comp_c[tid] = tid & (CMAX - 1);
    if (tid == 0) doneFlag[0] = 0;

    const int wave = threadIdx.x >> 6, lane = threadIdx.x & 63;
    const int row = blockIdx.x * 4 + wave;
    const float4* r1 = (const float4*)(x1 + (size_t)row * D);
    const float4* r2 = (const float4*)(x2 + (size_t)row * D);
    float4 a0 = r1[lane * 2], a1 = r1[lane * 2 + 1];
    float4 b0 = r2[lane * 2], b1 = r2[lane * 2 + 1];
    ushort4* o1 = (ushort4*)(h1 + (size_t)row * D + lane * 8);
    ushort4* o2 = (ushort4*)(h2 + (size_t)row * D + lane * 8);
    o1[0] = make_ushort4(__builtin_bit_cast(u16, (_Float16)a0.x), __builtin_bit_cast(u16, (_Float16)a0.y),
                         __builtin_bit_cast(u16, (_Float16)a0.z), __builtin_bit_cast(u16, (_Float16)a0.w));
    o1[1] = make_ushort4(__builtin_bit_cast(u16, (_Float16)a1.x), __builtin_bit_cast(u16, (_Float16)a1.y),
                         __builtin_bit_cast(u16, (_Float16)a1.z), __builtin_bit_cast(u16, (_Float16)a1.w));
    o2[0] = make_ushort4(__builtin_bit_cast(u16, (_Float16)b0.x), __builtin_bit_cast(u16, (_Float16)b0.y),
                         __builtin_bit_cast(u16, (_Float16)b0.z), __builtin_bit_cast(u16, (_Float16)b0.w));
    o2[1] = make_ushort4(__builtin_bit_cast(u16, (_Float16)b1.x), __builtin_bit_cast(u16, (_Float16)b1.y),
                         __builtin_bit_cast(u16, (_Float16)b1.z), __builtin_bit_cast(u16, (_Float16)b1.w));
    float s1 = 0.f, s2 = 0.f, sr = 0.f;
    float av[8] = {a0.x, a0.y, a0.z, a0.w, a1.x, a1.y, a1.z, a1.w};
    float bv[8] = {b0.x, b0.y, b0.z, b0.w, b1.x, b1.y, b1.z, b1.w};
#pragma unroll
    for (int e = 0; e < 8; ++e) {
        s1 = fmaf(av[e], av[e], s1);
        s2 = fmaf(bv[e], bv[e], s2);
        float d = av[e] - bv[e];
        sr = fmaf(d, d, sr);
    }
#pragma unroll
    for (int off = 32; off > 0; off >>= 1) {
        s1 += __shfl_down(s1, off, 64);
        s2 += __shfl_down(s2, off, 64);
        sr += __shfl_down(sr, off, 64);
    }
    __shared__ float wsr[4];
    if (lane == 0) {
        sq[row] = s1;
        sq[N + row] = s2;
        wsr[wave] = sr;
    }
    __syncthreads();
    if (threadIdx.x == 0)
        accumArr[blockIdx.x] = wsr[0] + wsr[1] + wsr[2] + wsr[3];
}

// ---------------- single-pass f16 MFMA GEMM + dist epilogue + fused round-1 row argmin
// R15/R16 config (measured best) — unchanged.
#define BM 128
#define BN 128
#define BK 32

__global__ __launch_bounds__(256) void gemm_dist_kernel(const u16* __restrict__ h1,
                                                        const u16* __restrict__ h2,
                                                        const float* __restrict__ sqn,
                                                        float* __restrict__ dist1,
                                                        float* __restrict__ dist2,
                                                        u64* __restrict__ compBest) {
    const int m = blockIdx.z;
    const u16* H = m ? h2 : h1;
    const float* SQ = sqn + (size_t)m * N;
    float* dist = m ? dist2 : dist1;
    u64* cb = compBest + (size_t)m * N;

    __shared__ u16 SH[2 * BM * BK];
    u16* Ah = SH;
    u16* Bh = SH + BM * BK;

    const int tid = threadIdx.x;
    const int wave = tid >> 6, lane = tid & 63;
    const int wm = wave >> 1, wn = wave & 1;
    const int row0 = blockIdx.y * BM, col0 = blockIdx.x * BN;

    floatx4 acc[4][4] = {};

    const int srow = lane >> 2;
    const int scol = (lane & 3) * 8;

    for (int k0 = 0; k0 < D; k0 += BK) {
        __syncthreads();
#pragma unroll
        for (int i = 0; i < 2; ++i) {
            const int rb = wave * 32 + i * 16;
            const u16* ga = H + (size_t)(row0 + rb + srow) * D + k0 + scol;
            const u16* gb = H + (size_t)(col0 + rb + srow) * D + k0 + scol;
            __builtin_amdgcn_global_load_lds(
                (const __attribute__((address_space(1))) unsigned int*)ga,
                (__attribute__((address_space(3))) unsigned int*)&Ah[rb * BK], 16, 0, 0);
            __builtin_amdgcn_global_load_lds(
                (const __attribute__((address_space(1))) unsigned int*)gb,
                (__attribute__((address_space(3))) unsigned int*)&Bh[rb * BK], 16, 0, 0);
        }
        __syncthreads();

        const int fo = (lane >> 4) * 8;
        const int fm = lane & 15;
        f16x8 a8[4], b8[4];
#pragma unroll
        for (int s = 0; s < 4; ++s) {
            a8[s] = *(const f16x8*)&Ah[(wm * 64 + s * 16 + fm) * BK + fo];
            b8[s] = *(const f16x8*)&Bh[(wn * 64 + s * 16 + fm) * BK + fo];
        }
#pragma unroll
        for (int i = 0; i < 4; ++i)
#pragma unroll
            for (int j = 0; j < 4; ++j)
                acc[i][j] = __builtin_amdgcn_mfma_f32_16x16x32_f16(a8[i], b8[j], acc[i][j], 0, 0, 0);
    }

    __syncthreads();
    float* Cs = (float*)SH + wave * 1024;

    const int lr = lane & 15;
    const int lq = lane >> 4;
    float sc[4];
#pragma unroll
    for (int ns = 0; ns < 4; ++ns) sc[ns] = SQ[col0 + wn * 64 + ns * 16 + lr];
#pragma unroll
    for (int ms = 0; ms < 4; ++ms) {
        const int rb = row0 + wm * 64 + ms * 16 + lq * 4;
        float srow_[4];
#pragma unroll
        for (int r = 0; r < 4; ++r) srow_[r] = SQ[rb + r];
#pragma unroll
        for (int r = 0; r < 4; ++r) {
            const int row = rb + r;
            float dval[4];
#pragma unroll
            for (int ns = 0; ns < 4; ++ns) {
                const int col = col0 + wn * 64 + ns * 16 + lr;
                float d2 = srow_[r] + sc[ns] - 2.0f * acc[ms][ns][r];
                dval[ns] = (row == col) ? BIG : sqrtf(fmaxf(d2, 1e-12f));
            }
            float vmin = fminf(fminf(dval[0], dval[1]), fminf(dval[2], dval[3]));
            int nsel = (dval[0] == vmin) ? 0 : (dval[1] == vmin) ? 1 : (dval[2] == vmin) ? 2 : 3;
            u64 pmin = (((u64)__float_as_uint(vmin)) << 32) | (unsigned)(col0 + wn * 64 + nsel * 16 + lr);
#pragma unroll
            for (int msk = 1; msk < 16; msk <<= 1) {
                u64 o = __shfl_xor(pmin, msk, 64);
                pmin = o < pmin ? o : pmin;
            }
            if (lr == 0) atomicMin(&cb[row], pmin);
#pragma unroll
            for (int ns = 0; ns < 4; ++ns)
                Cs[(lq * 4 + r) * 64 + ns * 16 + lr] = dval[ns];
        }
#pragma unroll
        for (int p = 0; p < 4; ++p) {
            float4 v4 = *(float4*)&Cs[p * 256 + lane * 4];
            const int gr = row0 + wm * 64 + ms * 16 + p * 4 + (lane >> 4);
            const int gc = col0 + wn * 64 + (lane & 15) * 4;
            *(float4*)&dist[(size_t)gr * N + gc] = v4;
        }
    }
}

// ---------------- merge round 1 (blocks 0,1) + distc +inf init (blocks 2..1025)
__global__ __launch_bounds__(1024) void merge1i_kernel(int* __restrict__ comp,
                                                       u64* __restrict__ compBest,
                                                       float* __restrict__ deaths,
                                                       int* __restrict__ cnt,
                                                       int* __restrict__ numComp,
                                                       int* __restrict__ numC1,
                                                       unsigned* __restrict__ distc_u) {
    const int t = threadIdx.x;
    if (blockIdx.x >= 2) {
        // init distc: 2*CMAX*CMAX floats = 2,097,152 uint4; 1024 blocks x 1024 thr x 2
        const size_t idx = (size_t)(blockIdx.x - 2) * 1024 + t;
        uint4 v = make_uint4(0x7f800000u, 0x7f800000u, 0x7f800000u, 0x7f800000u);
        ((uint4*)distc_u)[idx] = v;
        ((uint4*)distc_u)[idx + 1048576] = v;
        return;
    }
    const int m = blockIdx.x;
    int* cp = comp + (size_t)m * N;
    u64* cb = compBest + (size_t)m * N;
    float* dth = deaths + (size_t)m * N;

    __shared__ int pa[N];
    __shared__ int pb[N];
    __shared__ unsigned flagbits[NW];
    __shared__ int wpc[NW];
    __shared__ int done;

    if (t == 0) cnt[m] = 0;
    __syncthreads();

    for (int c = t; c < N; c += 1024) {
        u64 best = cb[c];
        int p = c;
        if (best != ~0ull) {
            int j = (int)(unsigned)best;
            int c2 = cp[j];
            u64 best2 = cb[c2];
            int j2 = (int)(unsigned)best2;
            bool mutual = (cp[j2] == c);
            if (!(mutual && c < c2)) {
                p = c2;
                int idx = atomicAdd(cnt + m, 1);
                dth[idx] = __uint_as_float((unsigned)(best >> 32));
            }
        }
        pa[c] = p;
    }

    int* A = pa;
    int* B = pb;
    while (true) {
        __syncthreads();
        if (t == 0) done = 1;
        __syncthreads();
        bool ch = false;
        for (int c = t; c < N; c += 1024) {
            int g = A[A[c]];
            B[c] = g;
            ch |= (g != A[c]);
        }
        if (ch) done = 0;
        __syncthreads();
        int* tmp = A; A = B; B = tmp;
        if (done) break;
    }

    for (int w = t; w < NW; w += 1024) flagbits[w] = 0u;
    __syncthreads();
    for (int i = t; i < N; i += 1024)
        atomicOr(&flagbits[A[i] >> 5], 1u << (A[i] & 31));
    __syncthreads();
    if (t < NW) wpc[t] = __popc(flagbits[t]);
    __syncthreads();
    for (int off = 1; off < NW; off <<= 1) {
        int v = 0;
        if (t < NW) v = wpc[t] + ((t >= off) ? wpc[t - off] : 0);
        __syncthreads();
        if (t < NW) wpc[t] = v;
        __syncthreads();
    }
    for (int i = t; i < N; i += 1024) {
        int root = A[i];
        int w = root >> 5, b = root & 31;
        int base = w ? wpc[w - 1] : 0;
        unsigned mask = b ? ((1u << b) - 1u) : 0u;
        cp[i] = base + __popc(flagbits[w] & mask);
    }
    for (int c = t; c < N; c += 1024) cb[c] = ~0ull;
    if (t == 0) {
        int C1 = wpc[NW - 1];
        numC1[m] = C1;
        numComp[m] = C1;
    }
}

// ---------------- atomic level-1 contraction (per-row LDS bins -> global atomicMin)
__global__ __launch_bounds__(256) void rowatomic_kernel(const float* __restrict__ dist1,
                                                        const float* __restrict__ dist2,
                                                        const int* __restrict__ comp,
                                                        unsigned* __restrict__ distc_u) {
    const int m = blockIdx.y;
    const float* dist = m ? dist2 : dist1;
    const int* cp = comp + (size_t)m * N;
    const int i = blockIdx.x;
    const float4* row4 = (const float4*)(dist + (size_t)i * N);
    const int4* cp4 = (const int4*)cp;
    __shared__ unsigned bins[CMAX];
    const int t = threadIdx.x;
    for (int b = t; b < CMAX; b += 256) bins[b] = 0x7f800000u;
    __syncthreads();
#pragma unroll
    for (int k = 0; k < 4; ++k) {
        int q = t + 256 * k;
        float4 v = row4[q];
        int4 cj = cp4[q];
        atomicMin(&bins[cj.x], __float_as_uint(v.x));
        atomicMin(&bins[cj.y], __float_as_uint(v.y));
        atomicMin(&bins[cj.z], __float_as_uint(v.z));
        atomicMin(&bins[cj.w], __float_as_uint(v.w));
    }
    __syncthreads();
    unsigned* drow = distc_u + ((size_t)m * CMAX + cp[i]) * CMAX;
    for (int b = t; b < CMAX; b += 256) {
        unsigned v = bins[b];
        if (v != 0x7f800000u) atomicMin(&drow[b], v);
    }
}

// ---------------- round-2 scan on distc (blocks < 2*CMAX) + distc2 +inf init (rest)
__global__ __launch_bounds__(256) void scan_ci_kernel(const float* __restrict__ distc,
                                                      const int* __restrict__ comp_c,
                                                      u64* __restrict__ compBest,
                                                      const int* __restrict__ numComp,
                                                      const int* __restrict__ numC1,
                                                      unsigned* __restrict__ distc2_u) {
    const int t = threadIdx.x;
    if (blockIdx.x >= 2 * CMAX) {
        // init distc2: 2*CMAX2*CMAX2 floats = 524,288 uint4; 512 blocks x 256 thr x 4
        const size_t idx = (size_t)(blockIdx.x - 2 * CMAX) * 256 + t;
        uint4 v = make_uint4(0x7f800000u, 0x7f800000u, 0x7f800000u, 0x7f800000u);
#pragma unroll
        for (int k = 0; k < 4; ++k)
            ((uint4*)distc2_u)[idx + (size_t)k * 131072] = v;
        return;
    }
    const int m = blockIdx.x >> 11;          // CMAX = 2048
    if (numComp[m] <= 1) return;
    const int C1 = numC1[m];
    const int r = blockIdx.x & (CMAX - 1);
    if (r >= C1) return;
    const int* cc = comp_c + (size_t)m * CMAX;
    u64* cb = compBest + (size_t)m * N;
    const int myc = cc[r];
    const float4* row4 = (const float4*)(distc + ((size_t)m * CMAX + r) * CMAX);
    const int4* cc4 = (const int4*)cc;
    u64 best = ~0ull;
#pragma unroll
    for (int k = 0; k < 2; ++k) {
        int q = t + 256 * k;
        float4 v = row4[q];
        int4 cj = cc4[q];
        int j0 = q * 4;
        u64 p0 = (j0 + 0 < C1 && cj.x != myc) ? ((((u64)__float_as_uint(v.x)) << 32) | (unsigned)(j0 + 0)) : ~0ull;
        u64 p1 = (j0 + 1 < C1 && cj.y != myc) ? ((((u64)__float_as_uint(v.y)) << 32) | (unsigned)(j0 + 1)) : ~0ull;
        u64 p2 = (j0 + 2 < C1 && cj.z != myc) ? ((((u64)__float_as_uint(v.z)) << 32) | (unsigned)(j0 + 2)) : ~0ull;
        u64 p3 = (j0 + 3 < C1 && cj.w != myc) ? ((((u64)__float_as_uint(v.w)) << 32) | (unsigned)(j0 + 3)) : ~0ull;
        u64 q0 = p0 < p1 ? p0 : p1;
        u64 q1 = p2 < p3 ? p2 : p3;
        u64 qq = q0 < q1 ? q0 : q1;
        best = qq < best ? qq : best;
    }
#pragma unroll
    for (int off = 32; off > 0; off >>= 1) {
        u64 o = __shfl_down(best, off, 64);
        best = o < best ? o : best;
    }
    if ((t & 63) == 0) atomicMin(cb + myc, best);
}

// ---------------- merge round 2 (trimmed): hook + jump + dense relabel + comp_c2 identity
__global__ __launch_bounds__(1024) void merge2_kernel(int* __restrict__ comp_c,
                                                      u64* __restrict__ compBest,
                                                      float* __restrict__ deaths,
                                                      int* __restrict__ cnt,
                                                      int* __restrict__ numComp,
                                                      const int* __restrict__ numC1,
                                                      int* __restrict__ numC2,
                                                      int* __restrict__ comp_c2) {
    const int m = blockIdx.x;
    const int t = threadIdx.x;
    const int C1 = numC1[m];
    int* cc2i = comp_c2 + (size_t)m * CMAX2;
    for (int c = t; c < CMAX2; c += 1024) cc2i[c] = c;
    if (numComp[m] <= 1) {
        if (t == 0) numC2[m] = numComp[m];
        return;
    }
    int* cc = comp_c + (size_t)m * CMAX;
    u64* cb = compBest + (size_t)m * N;
    float* dth = deaths + (size_t)m * N;

    __shared__ int pa[CMAX];
    __shared__ int pb[CMAX];
    __shared__ unsigned flagbits[CMAX / 32];
    __shared__ int wpc[CMAX / 32];
    __shared__ int done;

    for (int c = t; c < C1; c += 1024) {
        u64 best = cb[c];
        int p = c;
        if (best != ~0ull) {
            int j = (int)(unsigned)best;
            int c2 = cc[j];
            u64 best2 = cb[c2];
            int j2 = (int)(unsigned)best2;
            bool mutual = (cc[j2] == c);
            if (!(mutual && c < c2)) {
                p = c2;
                int idx = atomicAdd(cnt + m, 1);
                dth[idx] = __uint_as_float((unsigned)(best >> 32));
            }
        }
        pa[c] = p;
    }

    int* A = pa;
    int* B = pb;
    while (true) {
        __syncthreads();
        if (t == 0) done = 1;
        __syncthreads();
        bool ch = false;
        for (int c = t; c < C1; c += 1024) {
            int g = A[A[c]];
            B[c] = g;
            ch |= (g != A[c]);
        }
        if (ch) done = 0;
        __syncthreads();
        int* tmp = A; A = B; B = tmp;
        if (done) break;
    }

    for (int w = t; w < CMAX / 32; w += 1024) flagbits[w] = 0u;
    __syncthreads();
    for (int j = t; j < C1; j += 1024)
        atomicOr(&flagbits[A[j] >> 5], 1u << (A[j] & 31));
    __syncthreads();
    if (t < CMAX / 32) wpc[t] = __popc(flagbits[t]);
    __syncthreads();
    for (int off = 1; off < CMAX / 32; off <<= 1) {
        int v = 0;
        if (t < CMAX / 32) v = wpc[t] + ((t >= off) ? wpc[t - off] : 0);
        __syncthreads();
        if (t < CMAX / 32) wpc[t] = v;
        __syncthreads();
    }
    for (int j = t; j < C1; j += 1024) {
        int root = A[j];
        int w = root >> 5, b = root & 31;
        int base = w ? wpc[w - 1] : 0;
        unsigned mask = b ? ((1u << b) - 1u) : 0u;
        cc[j] = base + __popc(flagbits[w] & mask);
    }
    for (int c = t; c < C1; c += 1024) cb[c] = ~0ull;
    if (t == 0) {
        int C2 = wpc[CMAX / 32 - 1];
        numC2[m] = C2;
        numComp[m] = C2;
    }
}

// ---------------- atomic level-2 contraction: row of distc -> bins[C2] -> distc2
__global__ __launch_bounds__(256) void rowatomic2_kernel(const float* __restrict__ distc,
                                                         const int* __restrict__ comp_c,
                                                         const int* __restrict__ numComp,
                                                         const int* __restrict__ numC1,
                                                         unsigned* __restrict__ distc2_u) {
    const int m = blockIdx.y;
    if (numComp[m] <= 1) return;
    const int C1 = numC1[m];
    const int r = blockIdx.x;
    if (r >= C1) return;
    const int* cc = comp_c + (size_t)m * CMAX;
    const float* row = distc + ((size_t)m * CMAX + r) * CMAX;
    __shared__ unsigned bins[CMAX2];
    const int t = threadIdx.x;
    for (int b = t; b < CMAX2; b += 256) bins[b] = 0x7f800000u;
    __syncthreads();
    for (int j = t; j < C1; j += 256)
        atomicMin(&bins[cc[j]], __float_as_uint(row[j]));
    __syncthreads();
    unsigned* drow = distc2_u + ((size_t)m * CMAX2 + cc[r]) * CMAX2;
    for (int b = t; b < CMAX2; b += 256) {
        unsigned v = bins[b];
        if (v != 0x7f800000u) atomicMin(&drow[b], v);
    }
}

// ---------------- finish: rounds >= 3 + fused sort + last-block fused final
__global__ __launch_bounds__(1024) void finish_kernel(const float* __restrict__ distc2,
                                                      const int* __restrict__ comp_c2,
                                                      float* __restrict__ deaths,
                                                      int* __restrict__ cnt,
                                                      int* __restrict__ numComp,
                                                      const int* __restrict__ numC2,
                                                      const float* __restrict__ accumArr,
                                                      int* __restrict__ doneFlag,
                                                      float* __restrict__ out) {
    const int m = blockIdx.x;
    int nc = numComp[m];
    const int C2 = numC2[m];
    const float* Dm = distc2 + (size_t)m * CMAX2 * CMAX2;
    float* dth = deaths + (size_t)m * N;
    const int t = threadIdx.x;
    const int wave = t >> 6, lane = t & 63;
    __shared__ int comp[CMAX2];
    __shared__ u64 cb[CMAX2];
    __shared__ int pa[CMAX2];
    __shared__ int pb[CMAX2];
    __shared__ unsigned flags[CMAX2 / 32];
    __shared__ int done, ncs, lastf;
    __shared__ float s[N];
    __shared__ float wsum[16];
    __shared__ float rsum[16];

    if (nc > 1) {
        for (int c = t; c < C2; c += 1024) {
            comp[c] = comp_c2[(size_t)m * CMAX2 + c];
            cb[c] = ~0ull;
        }
        __syncthreads();

        for (int round = 0; round < 10 && nc > 1; ++round) {
            for (int r = wave; r < C2; r += 16) {
                const int myc = comp[r];
                const float* row = Dm + (size_t)r * CMAX2;
                u64 best = ~0ull;
                for (int j = lane; j < C2; j += 64) {
                    if (comp[j] != myc) {
                        u64 p = (((u64)__float_as_uint(row[j])) << 32) | (unsigned)j;
                        best = p < best ? p : best;
                    }
                }
#pragma unroll
                for (int off = 32; off > 0; off >>= 1) {
                    u64 o = __shfl_down(best, off, 64);
                    best = o < best ? o : best;
                }
                if (lane == 0) atomicMin(&cb[myc], best);
            }
            __syncthreads();
            for (int c = t; c < C2; c += 1024) {
                u64 best = cb[c];
                int p = c;
                if (best != ~0ull) {
                    int j = (int)(unsigned)best;
                    int c2 = comp[j];
                    u64 best2 = cb[c2];
                    int j2 = (int)(unsigned)best2;
                    bool mutual = (comp[j2] == c);
                    if (!(mutual && c < c2)) {
                        p = c2;
                        int idx = atomicAdd(cnt + m, 1);
                        dth[idx] = __uint_as_float((unsigned)(best >> 32));
                    }
                }
                pa[c] = p;
            }
            int* A = pa; int* B = pb;
            while (true) {
                __syncthreads();
                if (t == 0) done = 1;
                __syncthreads();
                bool ch = false;
                for (int c = t; c < C2; c += 1024) {
                    int g = A[A[c]];
                    B[c] = g;
                    ch |= (g != A[c]);
                }
                if (ch) done = 0;
                __syncthreads();
                int* tmp = A; A = B; B = tmp;
                if (done) break;
            }
            for (int w = t; w < CMAX2 / 32; w += 1024) flags[w] = 0u;
            __syncthreads();
            for (int j = t; j < C2; j += 1024) {
                int root = A[comp[j]];
                comp[j] = root;
                atomicOr(&flags[root >> 5], 1u << (root & 31));
            }
            for (int c = t; c < C2; c += 1024) cb[c] = ~0ull;
            __syncthreads();
            if (t == 0) {
                int sacc = 0;
                for (int w = 0; w < CMAX2 / 32; ++w) sacc += __popc(flags[w]);
                ncs = sacc;
            }
            __syncthreads();
            nc = ncs;
        }
        if (t == 0) numComp[m] = nc;
    }
    __syncthreads();

    // fused bitonic sort of this matrix's deaths
    for (int i = t; i < N; i += 1024)
        s[i] = (i < N - 1) ? dth[i] : BIG;
    __syncthreads();
    for (int k = 2; k <= N; k <<= 1) {
        for (int jj = k >> 1; jj > 0; jj >>= 1) {
            for (int i = t; i < N; i += 1024) {
                int ixj = i ^ jj;
                if (ixj > i) {
                    float a = s[i], b = s[ixj];
                    bool up = ((i & k) == 0);
                    bool sw = up ? (a > b) : (a < b);
                    if (sw) { s[i] = b; s[ixj] = a; }
                }
            }
            __syncthreads();
        }
    }
    for (int i = t; i < N; i += 1024) dth[i] = s[i];

    // last-block fused final (device-scope ticket; grid-order independent)
    __threadfence();
    __syncthreads();
    if (t == 0) lastf = (atomicAdd(doneFlag, 1) == 1) ? 1 : 0;
    __syncthreads();
    if (!lastf) return;
    __threadfence();
    const float* s1 = deaths;
    const float* s2 = deaths + N;
    float sum = 0.f;
    for (int i = t; i < N - 1; i += 1024) {
        float a = s1[i], b = s2[i];
        sum += fminf(fabsf(a - b), 0.5f * (a + b));
    }
    float ra = accumArr[t];
#pragma unroll
    for (int off = 32; off > 0; off >>= 1) {
        sum += __shfl_down(sum, off, 64);
        ra += __shfl_down(ra, off, 64);
    }
    if (lane == 0) { wsum[wave] = sum; rsum[wave] = ra; }
    __syncthreads();
    if (t == 0) {
        float tot = 0.f, rt = 0.f;
        for (int k = 0; k < 16; ++k) { tot += wsum[k]; rt += rsum[k]; }
        out[0] = rt * (1.0f / ((float)N * (float)D)) + tot;
    }
}

extern "C" void kernel_launch(void* const* d_in, const int* in_sizes, int n_in,
                              void* d_out, int out_size, void* d_ws, size_t ws_size,
                              hipStream_t stream) {
    const float* x1 = (const float*)d_in[0];
    const float* x2 = (const float*)d_in[1];
    float* out = (float*)d_out;
    float* ws = (float*)d_ws;

    const size_t nn = (size_t)N * N;
    const size_t cc2 = (size_t)CMAX * CMAX;

    float* dist1 = ws;
    float* dist2 = ws + nn;
    float* distc = ws + 2 * nn;
    u16* h1 = (u16*)distc;                 // alias: dead before merge1i's init overwrites
    u16* h2 = h1 + (size_t)N * D;
    u64* compBest = (u64*)(distc + 2 * cc2);
    int* comp      = (int*)(compBest + 2 * N);
    int* comp_c    = comp + 2 * N;
    float* deaths  = (float*)(comp_c + 2 * CMAX);
    int* cnt       = (int*)(deaths + 2 * N);
    int* numComp   = cnt + 2;
    int* numC1     = numComp + 2;
    int* numC2     = numC1 + 2;
    int* doneFlag  = numC2 + 2;
    float* sq      = (float*)(doneFlag + 2);
    float* accumArr = sq + 2 * N;          // 1024 floats
    // level-2 buffers alias dist1 (dead after rowatomic) — distc2 init'd in scan_ci,
    // comp_c2 in merge2. NEVER earlier (R7 crash lesson).
    float* distc2  = dist1;
    int* comp_c2   = (int*)(distc2 + 2 * (size_t)CMAX2 * CMAX2);

    prep_kernel<<<N / 4, 256, 0, stream>>>(x1, x2, h1, h2, sq, accumArr, comp, compBest,
                                           comp_c, doneFlag);
    gemm_dist_kernel<<<dim3(N / BN, N / BM, 2), 256, 0, stream>>>(h1, h2, sq, dist1, dist2, compBest);
    merge1i_kernel<<<2 + 1024, 1024, 0, stream>>>(comp, compBest, deaths, cnt, numComp, numC1,
                                                  (unsigned*)distc);
    rowatomic_kernel<<<dim3(N, 2), 256, 0, stream>>>(dist1, dist2, comp, (unsigned*)distc);
    scan_ci_kernel<<<2 * CMAX + 512, 256, 0, stream>>>(distc, comp_c, compBest, numComp, numC1,
                                                       (unsigned*)distc2);
    merge2_kernel<<<2, 1024, 0, stream>>>(comp_c, compBest, deaths, cnt, numComp, numC1, numC2,
                                          comp_c2);
    rowatomic2_kernel<<<dim3(CMAX, 2), 256, 0, stream>>>(distc, comp_c, numComp, numC1,
                                                         (unsigned*)distc2);
    finish_kernel<<<2, 1024, 0, stream>>>(distc2, comp_c2, deaths, cnt, numComp, numC2,
                                          accumArr, doneFlag, out);
}